// Round 11
// baseline (5560.519 us; speedup 1.0000x reference)
//
#include <hip/hip_runtime.h>
#include <hip/hip_bf16.h>

using bf16x8 = __attribute__((ext_vector_type(8))) __bf16;
using short8 = __attribute__((ext_vector_type(8))) short;
using f32x4  = __attribute__((ext_vector_type(4))) float;
using f4     = __attribute__((ext_vector_type(4))) float;
using i32x4  = __attribute__((ext_vector_type(4))) int;

constexpr int NB = 128;
constexpr int NT = 256;
constexpr int NH = 1024;
constexpr int NE = 256;
constexpr int NV = 256;
constexpr int BH = NB * NH;

constexpr int WHH_BYTES = 48 * 2048;    // 98304
constexpr int NTILE     = 60;           // 36 hh + 24 input partial tiles
constexpr int GH_FLOATS = NTILE * 256;  // 61440 B

// ---- cache-bypass (coherence-point) ops ----
__device__ __forceinline__ void ldg_sc(i32x4& d, const void* p) {
  asm volatile("global_load_dwordx4 %0, %1, off sc0 sc1" : "=v"(d) : "v"(p));
}
__device__ __forceinline__ void stg_sc(void* p, i32x4 v) {
  asm volatile("global_store_dwordx4 %0, %1, off sc0 sc1" :: "v"(p), "v"(v) : "memory");
}
__device__ __forceinline__ void vm0_fence() {
  asm volatile("s_waitcnt vmcnt(0)" ::: "memory");
}
__device__ __forceinline__ void use_dep(i32x4& d) {
  asm volatile("" : "+v"(d));
}

__device__ __forceinline__ bf16x8 cvt8(const float* p) {
  short8 r;
  #pragma unroll
  for (int j = 0; j < 8; ++j)
    r[j] = (short)__bfloat16_as_ushort(__float2bfloat16(p[j]));
  return __builtin_bit_cast(bf16x8, r);
}

__global__ __launch_bounds__(256) void embcvt_kernel(const float* __restrict__ e,
                                                     __hip_bfloat16* __restrict__ o) {
  int i = blockIdx.x * 256 + threadIdx.x;
  o[i] = __float2bfloat16(e[i]);
}

// Fused 2-layer GRU, 257 pipelined periods. 256 WGs x 384 thr:
// even blocks = layer0, odd = layer1. WG owns h'[rb2*64:+64, c0:+16].
// Wave (mt,ks): hh GEMM m-tiles {mt, mt+2}, k-slice ks, all 3 gates;
// input GEMM gate ks, K-half mt, all 4 m-tiles (VGPR frags <=16).
// L0: A from Ys[t-1] (sc; t=0 from h0), publish Ys[t]+flag0.
// L1: h1 via hbuf1[2] (sc)+flag1; input = cached reads of Ys[t]
// (stale-L2 killed by one agent acquire fence at start).
__global__ __launch_bounds__(384, 2) void gru_fused(
    const int* __restrict__ x,
    const __hip_bfloat16* __restrict__ embb,
    const float* __restrict__ Wih0, const float* __restrict__ Whh0,
    const float* __restrict__ bih0, const float* __restrict__ bhh0,
    const float* __restrict__ Wih1, const float* __restrict__ Whh1,
    const float* __restrict__ bih1, const float* __restrict__ bhh1,
    const float* __restrict__ h0,          // [2][128][1024]
    __hip_bfloat16* __restrict__ Ys,       // [256][128][1024] state-after-t
    __hip_bfloat16* __restrict__ hbuf1,    // [2][128][1024]
    float* __restrict__ hout,              // [2][128][1024] f32
    unsigned int* __restrict__ flags)      // [2][2][64][16]
{
  extern __shared__ char smem[];
  char*  sWhh  = smem;
  float* sGh   = (float*)(smem + WHH_BYTES);
  float* sBias = sGh + GH_FLOATS;
  char*  sH    = (char*)(sBias + 64);      // 64x16 bf16 (2KB)

  const int tid   = threadIdx.x;
  const int lane  = tid & 63;
  const int wv    = tid >> 6;
  const int mt    = wv & 1;
  const int ks    = wv >> 1;
  const int b     = blockIdx.x;
  const int layer = b & 1;
  const int idx   = b >> 1;
  const int rb2   = idx & 1;
  const int cidx  = idx >> 1;              // 0..63
  const int r0    = rb2 * 64;
  const int c0    = cidx * 16;
  unsigned int* flagL  = flags + (layer * 2 + rb2) * 64 * 16;
  unsigned int* flag0g = flags + (rb2) * 64 * 16;       // layer0, same rb2
  const int l16 = lane & 15;
  const int lk8 = (lane >> 4) * 8;

  const float* Wih = layer ? Wih1 : Wih0;
  const float* Whh = layer ? Whh1 : Whh0;
  const float* bih = layer ? bih1 : bih0;
  const float* bhh = layer ? bhh1 : bhh0;
  const float* h0l = h0 + layer * BH;
  float* houtl = hout + layer * BH;

  // ---- stage own-layer W_hh slice (48 gate-rows x 1024) swizzled ----
  for (int it = 0; it < 16; ++it) {
    int id2 = it * 384 + tid;
    int gr = id2 >> 7, kc = id2 & 127;
    int grow = (gr >> 4) * NH + c0 + (gr & 15);
    short8 v = __builtin_bit_cast(short8, cvt8(Whh + grow * NH + kc * 8));
    *(short8*)(sWhh + ((gr * 2048 + kc * 16) ^ ((gr & 7) << 4))) = v;
  }
  if (tid < 16)       sBias[tid] = bih[c0 + tid] + bhh[c0 + tid];
  else if (tid < 32)  { int c = NH + c0 + tid - 16;   sBias[tid] = bih[c] + bhh[c]; }
  else if (tid < 48)  { int c = 2*NH + c0 + tid - 32; sBias[tid] = bih[c]; }
  else if (tid < 64)  { int c = 2*NH + c0 + tid - 48; sBias[tid] = bhh[c]; }

  // ---- W_ih VGPR fragments: gate ks, K-half mt ----
  bf16x8 wreg[16];
  if (layer == 0) {
    #pragma unroll
    for (int kf = 0; kf < 4; ++kf)
      wreg[kf] = cvt8(Wih + (ks * NH + c0 + l16) * NE + mt * 128 + kf * 32 + lk8);
  } else {
    #pragma unroll
    for (int kf = 0; kf < 16; ++kf)
      wreg[kf] = cvt8(Wih + (ks * NH + c0 + l16) * NH + mt * 512 + kf * 32 + lk8);
  }

  // ---- init: h -> regs + sH; L1 publishes hbuf1[0]+flag=1; fence ----
  float hown[3] = {0.f, 0.f, 0.f};
  #pragma unroll
  for (int ei = 0; ei < 3; ++ei) {
    int e = tid + ei * 384;
    if (e < 1024) {
      int row = e >> 4, col = e & 15;
      float hv = h0l[(r0 + row) * NH + c0 + col];
      hown[ei] = hv;
      ((unsigned short*)sH)[e] = __bfloat16_as_ushort(__float2bfloat16(hv));
    }
  }
  __syncthreads();
  if (layer == 1) {
    if (tid < 128) {
      i32x4 hv = *(const i32x4*)(sH + (tid >> 1) * 32 + (tid & 1) * 16);
      stg_sc(hbuf1 + (r0 + (tid >> 1)) * NH + c0 + (tid & 1) * 8, hv);
    }
    vm0_fence();
    if (tid == 0)
      __hip_atomic_store(flagL + cidx * 16, 1u, __ATOMIC_RELAXED,
                         __HIP_MEMORY_SCOPE_AGENT);
    // one-time L2 invalidate: kills stale Ys lines from prior graph replays
    __builtin_amdgcn_fence(__ATOMIC_ACQUIRE, "agent");
  }

  const int bxor = (l16 & 7) << 4;
  float* abase = sGh + (lane >> 4) * 64 + l16;
  const int nk = (ks < 2) ? 11 : 10;
  const int bb0 = (l16)      * 2048 + lk8 * 2;
  const int bb1 = (16 + l16) * 2048 + lk8 * 2;
  const int bb2 = (32 + l16) * 2048 + lk8 * 2;

  if (layer == 0) {
    // ================= LAYER 0 =================
    for (int t = 0; t < NT; ++t) {
      // 1. input GEMM (emb gather), 4 m-tiles, partials -> tiles
      #pragma unroll
      for (int m4 = 0; m4 < 4; ++m4) {
        int xid = x[(r0 + m4 * 16 + l16) * NT + t];
        const __hip_bfloat16* xp = embb + xid * NE + mt * 128 + lk8;
        f32x4 ii = {0.f, 0.f, 0.f, 0.f};
        #pragma unroll
        for (int kf = 0; kf < 4; ++kf) {
          bf16x8 a = __builtin_bit_cast(bf16x8, *(const short8*)(xp + kf * 32));
          ii = __builtin_amdgcn_mfma_f32_16x16x32_bf16(a, wreg[kf], ii, 0, 0, 0);
        }
        float* p = abase + (36 + (ks * 2 + mt) * 4 + m4) * 256;
        p[0] = ii[0]; p[16] = ii[1]; p[32] = ii[2]; p[48] = ii[3];
      }
      // 2. wait peers' Ys[t-1]
      if (t > 0 && tid < 64) {
        unsigned int ep = (unsigned int)(t + 1);
        const unsigned int* f = flagL + tid * 16;
        while (__hip_atomic_load(f, __ATOMIC_RELAXED,
                                 __HIP_MEMORY_SCOPE_AGENT) < ep)
          __builtin_amdgcn_s_sleep(1);
      }
      __syncthreads();
      // 3. A loads (2 m-tiles x k-slice) + hh MFMAs
      i32x4 fr0[11], fr1[11];
      if (t == 0) {
        #pragma unroll
        for (int i = 0; i < 11; ++i)
          if (i < nk) {
            int kk = ks + 3 * i;
            fr0[i] = __builtin_bit_cast(i32x4, cvt8(h0l + (r0 + mt*16 + l16) * NH + kk*32 + lk8));
            fr1[i] = __builtin_bit_cast(i32x4, cvt8(h0l + (r0 + (2+mt)*16 + l16) * NH + kk*32 + lk8));
          }
      } else {
        const __hip_bfloat16* ap0 = Ys + (size_t)(t-1) * BH + (r0 + mt*16 + l16) * NH + lk8;
        const __hip_bfloat16* ap1 = Ys + (size_t)(t-1) * BH + (r0 + (2+mt)*16 + l16) * NH + lk8;
        #pragma unroll
        for (int i = 0; i < 11; ++i)
          if (i < nk) { ldg_sc(fr0[i], ap0 + (ks + 3*i) * 32); ldg_sc(fr1[i], ap1 + (ks + 3*i) * 32); }
        vm0_fence();
        #pragma unroll
        for (int i = 0; i < 11; ++i)
          if (i < nk) { use_dep(fr0[i]); use_dep(fr1[i]); }
      }
      {
        f32x4 a0g0={0,0,0,0}, a0g1={0,0,0,0}, a0g2={0,0,0,0};
        f32x4 a1g0={0,0,0,0}, a1g1={0,0,0,0}, a1g2={0,0,0,0};
        #pragma unroll
        for (int i = 0; i < 11; ++i) {
          if (i < nk) {
            int kk = ks + 3 * i;
            bf16x8 b0 = __builtin_bit_cast(bf16x8, *(const short8*)(sWhh + ((bb0 + kk*64) ^ bxor)));
            bf16x8 b1 = __builtin_bit_cast(bf16x8, *(const short8*)(sWhh + ((bb1 + kk*64) ^ bxor)));
            bf16x8 b2 = __builtin_bit_cast(bf16x8, *(const short8*)(sWhh + ((bb2 + kk*64) ^ bxor)));
            bf16x8 a0 = __builtin_bit_cast(bf16x8, fr0[i]);
            bf16x8 a1 = __builtin_bit_cast(bf16x8, fr1[i]);
            a0g0 = __builtin_amdgcn_mfma_f32_16x16x32_bf16(a0, b0, a0g0, 0, 0, 0);
            a0g1 = __builtin_amdgcn_mfma_f32_16x16x32_bf16(a0, b1, a0g1, 0, 0, 0);
            a0g2 = __builtin_amdgcn_mfma_f32_16x16x32_bf16(a0, b2, a0g2, 0, 0, 0);
            a1g0 = __builtin_amdgcn_mfma_f32_16x16x32_bf16(a1, b0, a1g0, 0, 0, 0);
            a1g1 = __builtin_amdgcn_mfma_f32_16x16x32_bf16(a1, b1, a1g1, 0, 0, 0);
            a1g2 = __builtin_amdgcn_mfma_f32_16x16x32_bf16(a1, b2, a1g2, 0, 0, 0);
          }
        }
        float* p;
        p = abase + ((ks*4 + mt)*3 + 0)*256;   p[0]=a0g0[0];p[16]=a0g0[1];p[32]=a0g0[2];p[48]=a0g0[3];
        p = abase + ((ks*4 + mt)*3 + 1)*256;   p[0]=a0g1[0];p[16]=a0g1[1];p[32]=a0g1[2];p[48]=a0g1[3];
        p = abase + ((ks*4 + mt)*3 + 2)*256;   p[0]=a0g2[0];p[16]=a0g2[1];p[32]=a0g2[2];p[48]=a0g2[3];
        p = abase + ((ks*4 + 2+mt)*3 + 0)*256; p[0]=a1g0[0];p[16]=a1g0[1];p[32]=a1g0[2];p[48]=a1g0[3];
        p = abase + ((ks*4 + 2+mt)*3 + 1)*256; p[0]=a1g1[0];p[16]=a1g1[1];p[32]=a1g1[2];p[48]=a1g1[3];
        p = abase + ((ks*4 + 2+mt)*3 + 2)*256; p[0]=a1g2[0];p[16]=a1g2[1];p[32]=a1g2[2];p[48]=a1g2[3];
      }
      __syncthreads();
      // 4. gates
      #pragma unroll
      for (int ei = 0; ei < 3; ++ei) {
        int e = tid + ei * 384;
        if (e < 1024) {
          int lrow = e >> 4, lcol = e & 15;
          int m4 = lrow >> 4, off = (lrow & 15) * 16 + lcol;
          float ghr = sGh[((0*4+m4)*3+0)*256+off] + sGh[((1*4+m4)*3+0)*256+off] + sGh[((2*4+m4)*3+0)*256+off];
          float ghz = sGh[((0*4+m4)*3+1)*256+off] + sGh[((1*4+m4)*3+1)*256+off] + sGh[((2*4+m4)*3+1)*256+off];
          float ghn = sGh[((0*4+m4)*3+2)*256+off] + sGh[((1*4+m4)*3+2)*256+off] + sGh[((2*4+m4)*3+2)*256+off];
          float gir = sGh[(36+0*4+m4)*256+off] + sGh[(36+1*4+m4)*256+off];
          float giz = sGh[(36+2*4+m4)*256+off] + sGh[(36+3*4+m4)*256+off];
          float gin = sGh[(36+4*4+m4)*256+off] + sGh[(36+5*4+m4)*256+off];
          float r = 1.f / (1.f + __expf(-(gir + ghr + sBias[lcol])));
          float z = 1.f / (1.f + __expf(-(giz + ghz + sBias[16 + lcol])));
          float npre = (gin + sBias[32 + lcol]) + r * (ghn + sBias[48 + lcol]);
          float n = 2.f / (1.f + __expf(-2.f * npre)) - 1.f;
          float hn = (1.f - z) * n + z * hown[ei];
          hown[ei] = hn;
          ((unsigned short*)sH)[e] = __bfloat16_as_ushort(__float2bfloat16(hn));
        }
      }
      __syncthreads();
      // 5. publish Ys[t] + flag
      if (tid < 128) {
        i32x4 hv = *(const i32x4*)(sH + (tid >> 1) * 32 + (tid & 1) * 16);
        stg_sc(Ys + (size_t)t * BH + (r0 + (tid >> 1)) * NH + c0 + (tid & 1) * 8, hv);
      }
      vm0_fence();
      if (tid == 0)
        __hip_atomic_store(flagL + cidx * 16, (unsigned int)(t + 2),
                           __ATOMIC_RELAXED, __HIP_MEMORY_SCOPE_AGENT);
    }
  } else {
    // ================= LAYER 1 =================
    for (int t = 0; t < NT; ++t) {
      // 1. wait own h1(t)
      if (tid < 64) {
        unsigned int ep = (unsigned int)(t + 1);
        const unsigned int* f = flagL + tid * 16;
        while (__hip_atomic_load(f, __ATOMIC_RELAXED,
                                 __HIP_MEMORY_SCOPE_AGENT) < ep)
          __builtin_amdgcn_s_sleep(1);
      }
      __syncthreads();
      // 2. A1 sc-loads from hbuf1[t&1]
      i32x4 fr0[11], fr1[11];
      {
        const __hip_bfloat16* ap0 = hbuf1 + (t & 1) * BH + (r0 + mt*16 + l16) * NH + lk8;
        const __hip_bfloat16* ap1 = hbuf1 + (t & 1) * BH + (r0 + (2+mt)*16 + l16) * NH + lk8;
        #pragma unroll
        for (int i = 0; i < 11; ++i)
          if (i < nk) { ldg_sc(fr0[i], ap0 + (ks + 3*i) * 32); ldg_sc(fr1[i], ap1 + (ks + 3*i) * 32); }
      }
      // 3. wait Ys[t] (steady state: already set)
      if (tid < 64) {
        unsigned int ep = (unsigned int)(t + 2);
        const unsigned int* f = flag0g + tid * 16;
        while (__hip_atomic_load(f, __ATOMIC_RELAXED,
                                 __HIP_MEMORY_SCOPE_AGENT) < ep)
          __builtin_amdgcn_s_sleep(1);
      }
      __syncthreads();
      // 4. input GEMM: cached reads of Ys[t] (L2-shared in group)
      #pragma unroll
      for (int m4 = 0; m4 < 4; ++m4) {
        const __hip_bfloat16* yp = Ys + (size_t)t * BH + (r0 + m4*16 + l16) * NH + mt * 512 + lk8;
        f32x4 ii = {0.f, 0.f, 0.f, 0.f};
        #pragma unroll
        for (int kf = 0; kf < 16; ++kf) {
          bf16x8 a = __builtin_bit_cast(bf16x8, *(const short8*)(yp + kf * 32));
          ii = __builtin_amdgcn_mfma_f32_16x16x32_bf16(a, wreg[kf], ii, 0, 0, 0);
        }
        float* p = abase + (36 + (ks * 2 + mt) * 4 + m4) * 256;
        p[0] = ii[0]; p[16] = ii[1]; p[32] = ii[2]; p[48] = ii[3];
      }
      // 5. hh MFMAs
      vm0_fence();
      #pragma unroll
      for (int i = 0; i < 11; ++i)
        if (i < nk) { use_dep(fr0[i]); use_dep(fr1[i]); }
      {
        f32x4 a0g0={0,0,0,0}, a0g1={0,0,0,0}, a0g2={0,0,0,0};
        f32x4 a1g0={0,0,0,0}, a1g1={0,0,0,0}, a1g2={0,0,0,0};
        #pragma unroll
        for (int i = 0; i < 11; ++i) {
          if (i < nk) {
            int kk = ks + 3 * i;
            bf16x8 b0 = __builtin_bit_cast(bf16x8, *(const short8*)(sWhh + ((bb0 + kk*64) ^ bxor)));
            bf16x8 b1 = __builtin_bit_cast(bf16x8, *(const short8*)(sWhh + ((bb1 + kk*64) ^ bxor)));
            bf16x8 b2 = __builtin_bit_cast(bf16x8, *(const short8*)(sWhh + ((bb2 + kk*64) ^ bxor)));
            bf16x8 a0 = __builtin_bit_cast(bf16x8, fr0[i]);
            bf16x8 a1 = __builtin_bit_cast(bf16x8, fr1[i]);
            a0g0 = __builtin_amdgcn_mfma_f32_16x16x32_bf16(a0, b0, a0g0, 0, 0, 0);
            a0g1 = __builtin_amdgcn_mfma_f32_16x16x32_bf16(a0, b1, a0g1, 0, 0, 0);
            a0g2 = __builtin_amdgcn_mfma_f32_16x16x32_bf16(a0, b2, a0g2, 0, 0, 0);
            a1g0 = __builtin_amdgcn_mfma_f32_16x16x32_bf16(a1, b0, a1g0, 0, 0, 0);
            a1g1 = __builtin_amdgcn_mfma_f32_16x16x32_bf16(a1, b1, a1g1, 0, 0, 0);
            a1g2 = __builtin_amdgcn_mfma_f32_16x16x32_bf16(a1, b2, a1g2, 0, 0, 0);
          }
        }
        float* p;
        p = abase + ((ks*4 + mt)*3 + 0)*256;   p[0]=a0g0[0];p[16]=a0g0[1];p[32]=a0g0[2];p[48]=a0g0[3];
        p = abase + ((ks*4 + mt)*3 + 1)*256;   p[0]=a0g1[0];p[16]=a0g1[1];p[32]=a0g1[2];p[48]=a0g1[3];
        p = abase + ((ks*4 + mt)*3 + 2)*256;   p[0]=a0g2[0];p[16]=a0g2[1];p[32]=a0g2[2];p[48]=a0g2[3];
        p = abase + ((ks*4 + 2+mt)*3 + 0)*256; p[0]=a1g0[0];p[16]=a1g0[1];p[32]=a1g0[2];p[48]=a1g0[3];
        p = abase + ((ks*4 + 2+mt)*3 + 1)*256; p[0]=a1g1[0];p[16]=a1g1[1];p[32]=a1g1[2];p[48]=a1g1[3];
        p = abase + ((ks*4 + 2+mt)*3 + 2)*256; p[0]=a1g2[0];p[16]=a1g2[1];p[32]=a1g2[2];p[48]=a1g2[3];
      }
      __syncthreads();
      // 6. gates
      #pragma unroll
      for (int ei = 0; ei < 3; ++ei) {
        int e = tid + ei * 384;
        if (e < 1024) {
          int lrow = e >> 4, lcol = e & 15;
          int m4 = lrow >> 4, off = (lrow & 15) * 16 + lcol;
          float ghr = sGh[((0*4+m4)*3+0)*256+off] + sGh[((1*4+m4)*3+0)*256+off] + sGh[((2*4+m4)*3+0)*256+off];
          float ghz = sGh[((0*4+m4)*3+1)*256+off] + sGh[((1*4+m4)*3+1)*256+off] + sGh[((2*4+m4)*3+1)*256+off];
          float ghn = sGh[((0*4+m4)*3+2)*256+off] + sGh[((1*4+m4)*3+2)*256+off] + sGh[((2*4+m4)*3+2)*256+off];
          float gir = sGh[(36+0*4+m4)*256+off] + sGh[(36+1*4+m4)*256+off];
          float giz = sGh[(36+2*4+m4)*256+off] + sGh[(36+3*4+m4)*256+off];
          float gin = sGh[(36+4*4+m4)*256+off] + sGh[(36+5*4+m4)*256+off];
          float r = 1.f / (1.f + __expf(-(gir + ghr + sBias[lcol])));
          float z = 1.f / (1.f + __expf(-(giz + ghz + sBias[16 + lcol])));
          float npre = (gin + sBias[32 + lcol]) + r * (ghn + sBias[48 + lcol]);
          float n = 2.f / (1.f + __expf(-2.f * npre)) - 1.f;
          float hn = (1.f - z) * n + z * hown[ei];
          hown[ei] = hn;
          ((unsigned short*)sH)[e] = __bfloat16_as_ushort(__float2bfloat16(hn));
        }
      }
      __syncthreads();
      // 7. publish hbuf1[(t+1)&1] + flag
      if (tid < 128) {
        i32x4 hv = *(const i32x4*)(sH + (tid >> 1) * 32 + (tid & 1) * 16);
        stg_sc(hbuf1 + ((t + 1) & 1) * BH + (r0 + (tid >> 1)) * NH + c0 + (tid & 1) * 8, hv);
      }
      vm0_fence();
      if (tid == 0)
        __hip_atomic_store(flagL + cidx * 16, (unsigned int)(t + 2),
                           __ATOMIC_RELAXED, __HIP_MEMORY_SCOPE_AGENT);
    }
  }

  #pragma unroll
  for (int ei = 0; ei < 3; ++ei) {
    int e = tid + ei * 384;
    if (e < 1024) {
      int row = e >> 4, col = e & 15;
      houtl[(r0 + row) * NH + c0 + col] = hown[ei];
    }
  }
}

__global__ __launch_bounds__(256) void logits_kernel(
    const __hip_bfloat16* __restrict__ h1,   // hbuf1 slot 0 = h1(256)
    const float* __restrict__ fcW,
    const float* __restrict__ fcb,
    float* __restrict__ out)
{
  __shared__ float hrow[NH];
  int b = blockIdx.x, v = threadIdx.x;
  if (v < 128) {
    i32x4 hv;
    ldg_sc(hv, h1 + b * NH + v * 8);
    vm0_fence();
    use_dep(hv);
    short8 s = __builtin_bit_cast(short8, hv);
    #pragma unroll
    for (int j = 0; j < 8; ++j) {
      union { unsigned int i; float f; } c;
      c.i = ((unsigned int)(unsigned short)s[j]) << 16;
      hrow[v * 8 + j] = c.f;
    }
  }
  __syncthreads();
  float acc = fcb[v];
  for (int k = 0; k < NH; k += 4) {
    f4 wv = *(const f4*)(fcW + v * NH + k);
    #pragma unroll
    for (int j = 0; j < 4; ++j) acc += wv[j] * hrow[k + j];
  }
  out[b * NV + v] = acc;
}

extern "C" void kernel_launch(void* const* d_in, const int* in_sizes, int n_in,
                              void* d_out, int out_size, void* d_ws, size_t ws_size,
                              hipStream_t stream) {
  const int*   x    = (const int*)d_in[0];
  const float* h0   = (const float*)d_in[1];
  const float* emb  = (const float*)d_in[2];
  const float* Wih0 = (const float*)d_in[3];
  const float* Whh0 = (const float*)d_in[4];
  const float* bih0 = (const float*)d_in[5];
  const float* bhh0 = (const float*)d_in[6];
  const float* Wih1 = (const float*)d_in[7];
  const float* Whh1 = (const float*)d_in[8];
  const float* bih1 = (const float*)d_in[9];
  const float* bhh1 = (const float*)d_in[10];
  const float* fcW  = (const float*)d_in[11];
  const float* fcb  = (const float*)d_in[12];
  float* out = (float*)d_out;

  char* ws = (char*)d_ws;
  size_t off = 0;
  __hip_bfloat16* Ys    = (__hip_bfloat16*)ws;           off += (size_t)NT * BH * 2;   // 64MB
  __hip_bfloat16* hbuf1 = (__hip_bfloat16*)(ws + off);   off += (size_t)2 * BH * 2;
  __hip_bfloat16* embb  = (__hip_bfloat16*)(ws + off);   off += (size_t)NV * NE * 2;
  unsigned int*   flags = (unsigned int*)(ws + off);     off += 2 * 2 * 64 * 16 * 4;

  (void)hipMemsetAsync(flags, 0, 2 * 2 * 64 * 16 * 4, stream);
  embcvt_kernel<<<dim3(NV * NE / 256), dim3(256), 0, stream>>>(emb, embb);

  constexpr int lds = WHH_BYTES + GH_FLOATS * 4 + 64 * 4 + 2048;  // 162048
  (void)hipFuncSetAttribute(reinterpret_cast<const void*>(gru_fused),
                            hipFuncAttributeMaxDynamicSharedMemorySize, lds);

  gru_fused<<<dim3(256), dim3(384), lds, stream>>>(
      x, embb, Wih0, Whh0, bih0, bhh0, Wih1, Whh1, bih1, bhh1,
      h0, Ys, hbuf1, out + 32768, flags);
  logits_kernel<<<dim3(NB), dim3(256), 0, stream>>>(hbuf1, fcW, fcb, out);
}

// Round 12
// 5505.377 us; speedup vs baseline: 1.0100x; 1.0100x over previous
//
#include <hip/hip_runtime.h>
#include <hip/hip_bf16.h>

using bf16x8 = __attribute__((ext_vector_type(8))) __bf16;
using short8 = __attribute__((ext_vector_type(8))) short;
using f32x4  = __attribute__((ext_vector_type(4))) float;
using f4     = __attribute__((ext_vector_type(4))) float;
using i32x4  = __attribute__((ext_vector_type(4))) int;

constexpr int NB = 128;
constexpr int NT = 256;
constexpr int NH = 1024;
constexpr int NE = 256;
constexpr int NV = 256;
constexpr int BH = NB * NH;

constexpr int WHH_BYTES = 48 * 2048;    // 98304
constexpr int NTILE     = 60;           // 36 hh + 24 input partial tiles
constexpr int GH_FLOATS = NTILE * 256;  // 61440 B

// ---- cache-bypass (coherence-point) ops ----
__device__ __forceinline__ void ldg_sc(i32x4& d, const void* p) {
  asm volatile("global_load_dwordx4 %0, %1, off sc0 sc1" : "=v"(d) : "v"(p));
}
__device__ __forceinline__ void stg_sc(void* p, i32x4 v) {
  asm volatile("global_store_dwordx4 %0, %1, off sc0 sc1" :: "v"(p), "v"(v) : "memory");
}
__device__ __forceinline__ void vm0_fence() {
  asm volatile("s_waitcnt vmcnt(0)" ::: "memory");
}
__device__ __forceinline__ void use_dep(i32x4& d) {
  asm volatile("" : "+v"(d));
}

__device__ __forceinline__ bf16x8 cvt8(const float* p) {
  short8 r;
  #pragma unroll
  for (int j = 0; j < 8; ++j)
    r[j] = (short)__bfloat16_as_ushort(__float2bfloat16(p[j]));
  return __builtin_bit_cast(bf16x8, r);
}

__global__ __launch_bounds__(256) void embcvt_kernel(const float* __restrict__ e,
                                                     __hip_bfloat16* __restrict__ o) {
  int i = blockIdx.x * 256 + threadIdx.x;
  o[i] = __float2bfloat16(e[i]);
}

// Fused 2-layer GRU, 257 pipelined periods. 256 WGs x 384 thr:
// even blocks = layer0, odd = layer1. WG owns h'[rb2*64:+64, c0:+16].
// Wave (mt,ks): hh GEMM m-tiles {mt, mt+2}, k-slice ks, all 3 gates;
// input GEMM gate ks, K-half mt, all 4 m-tiles (VGPR frags <=16).
// L0: A from Ys[t-1] (sc; t=0 from h0), publish Ys[t]+flag0.
// L1: h1 via hbuf1[2] (sc)+flag1; input = cached reads of Ys[t]
// (stale-L2 killed by one agent acquire fence at start).
// launch_bounds(384,1): LDS already forces 1 block/CU (6 waves), so no
// VGPR clamp -- R11's (384,2) clamped to 128 and spilled ~70 regs/period.
__global__ __launch_bounds__(384, 1) void gru_fused(
    const int* __restrict__ x,
    const __hip_bfloat16* __restrict__ embb,
    const float* __restrict__ Wih0, const float* __restrict__ Whh0,
    const float* __restrict__ bih0, const float* __restrict__ bhh0,
    const float* __restrict__ Wih1, const float* __restrict__ Whh1,
    const float* __restrict__ bih1, const float* __restrict__ bhh1,
    const float* __restrict__ h0,          // [2][128][1024]
    __hip_bfloat16* __restrict__ Ys,       // [256][128][1024] state-after-t
    __hip_bfloat16* __restrict__ hbuf1,    // [2][128][1024]
    float* __restrict__ hout,              // [2][128][1024] f32
    unsigned int* __restrict__ flags)      // [2][2][64][16]
{
  extern __shared__ char smem[];
  char*  sWhh  = smem;
  float* sGh   = (float*)(smem + WHH_BYTES);
  float* sBias = sGh + GH_FLOATS;
  char*  sH    = (char*)(sBias + 64);      // 64x16 bf16 (2KB)

  const int tid   = threadIdx.x;
  const int lane  = tid & 63;
  const int wv    = tid >> 6;
  const int mt    = wv & 1;
  const int ks    = wv >> 1;
  const int b     = blockIdx.x;
  const int layer = b & 1;
  const int idx   = b >> 1;
  const int rb2   = idx & 1;
  const int cidx  = idx >> 1;              // 0..63
  const int r0    = rb2 * 64;
  const int c0    = cidx * 16;
  unsigned int* flagL  = flags + (layer * 2 + rb2) * 64 * 16;
  unsigned int* flag0g = flags + (rb2) * 64 * 16;       // layer0, same rb2
  const int l16 = lane & 15;
  const int lk8 = (lane >> 4) * 8;

  const float* Wih = layer ? Wih1 : Wih0;
  const float* Whh = layer ? Whh1 : Whh0;
  const float* bih = layer ? bih1 : bih0;
  const float* bhh = layer ? bhh1 : bhh0;
  const float* h0l = h0 + layer * BH;
  float* houtl = hout + layer * BH;

  // ---- stage own-layer W_hh slice (48 gate-rows x 1024) swizzled ----
  for (int it = 0; it < 16; ++it) {
    int id2 = it * 384 + tid;
    int gr = id2 >> 7, kc = id2 & 127;
    int grow = (gr >> 4) * NH + c0 + (gr & 15);
    short8 v = __builtin_bit_cast(short8, cvt8(Whh + grow * NH + kc * 8));
    *(short8*)(sWhh + ((gr * 2048 + kc * 16) ^ ((gr & 7) << 4))) = v;
  }
  if (tid < 16)       sBias[tid] = bih[c0 + tid] + bhh[c0 + tid];
  else if (tid < 32)  { int c = NH + c0 + tid - 16;   sBias[tid] = bih[c] + bhh[c]; }
  else if (tid < 48)  { int c = 2*NH + c0 + tid - 32; sBias[tid] = bih[c]; }
  else if (tid < 64)  { int c = 2*NH + c0 + tid - 48; sBias[tid] = bhh[c]; }

  // ---- W_ih VGPR fragments: gate ks, K-half mt ----
  bf16x8 wreg[16];
  if (layer == 0) {
    #pragma unroll
    for (int kf = 0; kf < 4; ++kf)
      wreg[kf] = cvt8(Wih + (ks * NH + c0 + l16) * NE + mt * 128 + kf * 32 + lk8);
  } else {
    #pragma unroll
    for (int kf = 0; kf < 16; ++kf)
      wreg[kf] = cvt8(Wih + (ks * NH + c0 + l16) * NH + mt * 512 + kf * 32 + lk8);
  }

  // ---- init: h -> regs + sH; L1 publishes hbuf1[0]+flag=1; fence ----
  float hown[3] = {0.f, 0.f, 0.f};
  #pragma unroll
  for (int ei = 0; ei < 3; ++ei) {
    int e = tid + ei * 384;
    if (e < 1024) {
      int row = e >> 4, col = e & 15;
      float hv = h0l[(r0 + row) * NH + c0 + col];
      hown[ei] = hv;
      ((unsigned short*)sH)[e] = __bfloat16_as_ushort(__float2bfloat16(hv));
    }
  }
  __syncthreads();
  if (layer == 1) {
    if (tid < 128) {
      i32x4 hv = *(const i32x4*)(sH + (tid >> 1) * 32 + (tid & 1) * 16);
      stg_sc(hbuf1 + (r0 + (tid >> 1)) * NH + c0 + (tid & 1) * 8, hv);
    }
    vm0_fence();
    if (tid == 0)
      __hip_atomic_store(flagL + cidx * 16, 1u, __ATOMIC_RELAXED,
                         __HIP_MEMORY_SCOPE_AGENT);
    // one-time L2 invalidate: kills stale Ys lines from prior graph replays
    __builtin_amdgcn_fence(__ATOMIC_ACQUIRE, "agent");
  }

  const int bxor = (l16 & 7) << 4;
  float* abase = sGh + (lane >> 4) * 64 + l16;
  const int nk = (ks < 2) ? 11 : 10;
  const int bb0 = (l16)      * 2048 + lk8 * 2;
  const int bb1 = (16 + l16) * 2048 + lk8 * 2;
  const int bb2 = (32 + l16) * 2048 + lk8 * 2;

  if (layer == 0) {
    // ================= LAYER 0 =================
    for (int t = 0; t < NT; ++t) {
      // 1. input GEMM (emb gather), 4 m-tiles, partials -> tiles
      #pragma unroll
      for (int m4 = 0; m4 < 4; ++m4) {
        int xid = x[(r0 + m4 * 16 + l16) * NT + t];
        const __hip_bfloat16* xp = embb + xid * NE + mt * 128 + lk8;
        f32x4 ii = {0.f, 0.f, 0.f, 0.f};
        #pragma unroll
        for (int kf = 0; kf < 4; ++kf) {
          bf16x8 a = __builtin_bit_cast(bf16x8, *(const short8*)(xp + kf * 32));
          ii = __builtin_amdgcn_mfma_f32_16x16x32_bf16(a, wreg[kf], ii, 0, 0, 0);
        }
        float* p = abase + (36 + (ks * 2 + mt) * 4 + m4) * 256;
        p[0] = ii[0]; p[16] = ii[1]; p[32] = ii[2]; p[48] = ii[3];
      }
      // 2. wait peers' Ys[t-1]
      if (t > 0 && tid < 64) {
        unsigned int ep = (unsigned int)(t + 1);
        const unsigned int* f = flagL + tid * 16;
        while (__hip_atomic_load(f, __ATOMIC_RELAXED,
                                 __HIP_MEMORY_SCOPE_AGENT) < ep)
          __builtin_amdgcn_s_sleep(1);
      }
      __syncthreads();
      // 3. A loads (2 m-tiles x k-slice) + hh MFMAs
      i32x4 fr0[11], fr1[11];
      if (t == 0) {
        #pragma unroll
        for (int i = 0; i < 11; ++i)
          if (i < nk) {
            int kk = ks + 3 * i;
            fr0[i] = __builtin_bit_cast(i32x4, cvt8(h0l + (r0 + mt*16 + l16) * NH + kk*32 + lk8));
            fr1[i] = __builtin_bit_cast(i32x4, cvt8(h0l + (r0 + (2+mt)*16 + l16) * NH + kk*32 + lk8));
          }
      } else {
        const __hip_bfloat16* ap0 = Ys + (size_t)(t-1) * BH + (r0 + mt*16 + l16) * NH + lk8;
        const __hip_bfloat16* ap1 = Ys + (size_t)(t-1) * BH + (r0 + (2+mt)*16 + l16) * NH + lk8;
        #pragma unroll
        for (int i = 0; i < 11; ++i)
          if (i < nk) { ldg_sc(fr0[i], ap0 + (ks + 3*i) * 32); ldg_sc(fr1[i], ap1 + (ks + 3*i) * 32); }
        vm0_fence();
        #pragma unroll
        for (int i = 0; i < 11; ++i)
          if (i < nk) { use_dep(fr0[i]); use_dep(fr1[i]); }
      }
      {
        f32x4 a0g0={0,0,0,0}, a0g1={0,0,0,0}, a0g2={0,0,0,0};
        f32x4 a1g0={0,0,0,0}, a1g1={0,0,0,0}, a1g2={0,0,0,0};
        #pragma unroll
        for (int i = 0; i < 11; ++i) {
          if (i < nk) {
            int kk = ks + 3 * i;
            bf16x8 b0 = __builtin_bit_cast(bf16x8, *(const short8*)(sWhh + ((bb0 + kk*64) ^ bxor)));
            bf16x8 b1 = __builtin_bit_cast(bf16x8, *(const short8*)(sWhh + ((bb1 + kk*64) ^ bxor)));
            bf16x8 b2 = __builtin_bit_cast(bf16x8, *(const short8*)(sWhh + ((bb2 + kk*64) ^ bxor)));
            bf16x8 a0 = __builtin_bit_cast(bf16x8, fr0[i]);
            bf16x8 a1 = __builtin_bit_cast(bf16x8, fr1[i]);
            a0g0 = __builtin_amdgcn_mfma_f32_16x16x32_bf16(a0, b0, a0g0, 0, 0, 0);
            a0g1 = __builtin_amdgcn_mfma_f32_16x16x32_bf16(a0, b1, a0g1, 0, 0, 0);
            a0g2 = __builtin_amdgcn_mfma_f32_16x16x32_bf16(a0, b2, a0g2, 0, 0, 0);
            a1g0 = __builtin_amdgcn_mfma_f32_16x16x32_bf16(a1, b0, a1g0, 0, 0, 0);
            a1g1 = __builtin_amdgcn_mfma_f32_16x16x32_bf16(a1, b1, a1g1, 0, 0, 0);
            a1g2 = __builtin_amdgcn_mfma_f32_16x16x32_bf16(a1, b2, a1g2, 0, 0, 0);
          }
        }
        float* p;
        p = abase + ((ks*4 + mt)*3 + 0)*256;   p[0]=a0g0[0];p[16]=a0g0[1];p[32]=a0g0[2];p[48]=a0g0[3];
        p = abase + ((ks*4 + mt)*3 + 1)*256;   p[0]=a0g1[0];p[16]=a0g1[1];p[32]=a0g1[2];p[48]=a0g1[3];
        p = abase + ((ks*4 + mt)*3 + 2)*256;   p[0]=a0g2[0];p[16]=a0g2[1];p[32]=a0g2[2];p[48]=a0g2[3];
        p = abase + ((ks*4 + 2+mt)*3 + 0)*256; p[0]=a1g0[0];p[16]=a1g0[1];p[32]=a1g0[2];p[48]=a1g0[3];
        p = abase + ((ks*4 + 2+mt)*3 + 1)*256; p[0]=a1g1[0];p[16]=a1g1[1];p[32]=a1g1[2];p[48]=a1g1[3];
        p = abase + ((ks*4 + 2+mt)*3 + 2)*256; p[0]=a1g2[0];p[16]=a1g2[1];p[32]=a1g2[2];p[48]=a1g2[3];
      }
      __syncthreads();
      // 4. gates
      #pragma unroll
      for (int ei = 0; ei < 3; ++ei) {
        int e = tid + ei * 384;
        if (e < 1024) {
          int lrow = e >> 4, lcol = e & 15;
          int m4 = lrow >> 4, off = (lrow & 15) * 16 + lcol;
          float ghr = sGh[((0*4+m4)*3+0)*256+off] + sGh[((1*4+m4)*3+0)*256+off] + sGh[((2*4+m4)*3+0)*256+off];
          float ghz = sGh[((0*4+m4)*3+1)*256+off] + sGh[((1*4+m4)*3+1)*256+off] + sGh[((2*4+m4)*3+1)*256+off];
          float ghn = sGh[((0*4+m4)*3+2)*256+off] + sGh[((1*4+m4)*3+2)*256+off] + sGh[((2*4+m4)*3+2)*256+off];
          float gir = sGh[(36+0*4+m4)*256+off] + sGh[(36+1*4+m4)*256+off];
          float giz = sGh[(36+2*4+m4)*256+off] + sGh[(36+3*4+m4)*256+off];
          float gin = sGh[(36+4*4+m4)*256+off] + sGh[(36+5*4+m4)*256+off];
          float r = 1.f / (1.f + __expf(-(gir + ghr + sBias[lcol])));
          float z = 1.f / (1.f + __expf(-(giz + ghz + sBias[16 + lcol])));
          float npre = (gin + sBias[32 + lcol]) + r * (ghn + sBias[48 + lcol]);
          float n = 2.f / (1.f + __expf(-2.f * npre)) - 1.f;
          float hn = (1.f - z) * n + z * hown[ei];
          hown[ei] = hn;
          ((unsigned short*)sH)[e] = __bfloat16_as_ushort(__float2bfloat16(hn));
        }
      }
      __syncthreads();
      // 5. publish Ys[t] + flag
      if (tid < 128) {
        i32x4 hv = *(const i32x4*)(sH + (tid >> 1) * 32 + (tid & 1) * 16);
        stg_sc(Ys + (size_t)t * BH + (r0 + (tid >> 1)) * NH + c0 + (tid & 1) * 8, hv);
      }
      vm0_fence();
      if (tid == 0)
        __hip_atomic_store(flagL + cidx * 16, (unsigned int)(t + 2),
                           __ATOMIC_RELAXED, __HIP_MEMORY_SCOPE_AGENT);
    }
  } else {
    // ================= LAYER 1 =================
    for (int t = 0; t < NT; ++t) {
      // 1. wait own h1(t)
      if (tid < 64) {
        unsigned int ep = (unsigned int)(t + 1);
        const unsigned int* f = flagL + tid * 16;
        while (__hip_atomic_load(f, __ATOMIC_RELAXED,
                                 __HIP_MEMORY_SCOPE_AGENT) < ep)
          __builtin_amdgcn_s_sleep(1);
      }
      __syncthreads();
      // 2. A1 sc-loads from hbuf1[t&1]
      i32x4 fr0[11], fr1[11];
      {
        const __hip_bfloat16* ap0 = hbuf1 + (t & 1) * BH + (r0 + mt*16 + l16) * NH + lk8;
        const __hip_bfloat16* ap1 = hbuf1 + (t & 1) * BH + (r0 + (2+mt)*16 + l16) * NH + lk8;
        #pragma unroll
        for (int i = 0; i < 11; ++i)
          if (i < nk) { ldg_sc(fr0[i], ap0 + (ks + 3*i) * 32); ldg_sc(fr1[i], ap1 + (ks + 3*i) * 32); }
      }
      // 3. wait Ys[t] (steady state: already set)
      if (tid < 64) {
        unsigned int ep = (unsigned int)(t + 2);
        const unsigned int* f = flag0g + tid * 16;
        while (__hip_atomic_load(f, __ATOMIC_RELAXED,
                                 __HIP_MEMORY_SCOPE_AGENT) < ep)
          __builtin_amdgcn_s_sleep(1);
      }
      __syncthreads();
      // 4. input GEMM: cached reads of Ys[t] (L2-shared in group)
      #pragma unroll
      for (int m4 = 0; m4 < 4; ++m4) {
        const __hip_bfloat16* yp = Ys + (size_t)t * BH + (r0 + m4*16 + l16) * NH + mt * 512 + lk8;
        f32x4 ii = {0.f, 0.f, 0.f, 0.f};
        #pragma unroll
        for (int kf = 0; kf < 16; ++kf) {
          bf16x8 a = __builtin_bit_cast(bf16x8, *(const short8*)(yp + kf * 32));
          ii = __builtin_amdgcn_mfma_f32_16x16x32_bf16(a, wreg[kf], ii, 0, 0, 0);
        }
        float* p = abase + (36 + (ks * 2 + mt) * 4 + m4) * 256;
        p[0] = ii[0]; p[16] = ii[1]; p[32] = ii[2]; p[48] = ii[3];
      }
      // 5. hh MFMAs
      vm0_fence();
      #pragma unroll
      for (int i = 0; i < 11; ++i)
        if (i < nk) { use_dep(fr0[i]); use_dep(fr1[i]); }
      {
        f32x4 a0g0={0,0,0,0}, a0g1={0,0,0,0}, a0g2={0,0,0,0};
        f32x4 a1g0={0,0,0,0}, a1g1={0,0,0,0}, a1g2={0,0,0,0};
        #pragma unroll
        for (int i = 0; i < 11; ++i) {
          if (i < nk) {
            int kk = ks + 3 * i;
            bf16x8 b0 = __builtin_bit_cast(bf16x8, *(const short8*)(sWhh + ((bb0 + kk*64) ^ bxor)));
            bf16x8 b1 = __builtin_bit_cast(bf16x8, *(const short8*)(sWhh + ((bb1 + kk*64) ^ bxor)));
            bf16x8 b2 = __builtin_bit_cast(bf16x8, *(const short8*)(sWhh + ((bb2 + kk*64) ^ bxor)));
            bf16x8 a0 = __builtin_bit_cast(bf16x8, fr0[i]);
            bf16x8 a1 = __builtin_bit_cast(bf16x8, fr1[i]);
            a0g0 = __builtin_amdgcn_mfma_f32_16x16x32_bf16(a0, b0, a0g0, 0, 0, 0);
            a0g1 = __builtin_amdgcn_mfma_f32_16x16x32_bf16(a0, b1, a0g1, 0, 0, 0);
            a0g2 = __builtin_amdgcn_mfma_f32_16x16x32_bf16(a0, b2, a0g2, 0, 0, 0);
            a1g0 = __builtin_amdgcn_mfma_f32_16x16x32_bf16(a1, b0, a1g0, 0, 0, 0);
            a1g1 = __builtin_amdgcn_mfma_f32_16x16x32_bf16(a1, b1, a1g1, 0, 0, 0);
            a1g2 = __builtin_amdgcn_mfma_f32_16x16x32_bf16(a1, b2, a1g2, 0, 0, 0);
          }
        }
        float* p;
        p = abase + ((ks*4 + mt)*3 + 0)*256;   p[0]=a0g0[0];p[16]=a0g0[1];p[32]=a0g0[2];p[48]=a0g0[3];
        p = abase + ((ks*4 + mt)*3 + 1)*256;   p[0]=a0g1[0];p[16]=a0g1[1];p[32]=a0g1[2];p[48]=a0g1[3];
        p = abase + ((ks*4 + mt)*3 + 2)*256;   p[0]=a0g2[0];p[16]=a0g2[1];p[32]=a0g2[2];p[48]=a0g2[3];
        p = abase + ((ks*4 + 2+mt)*3 + 0)*256; p[0]=a1g0[0];p[16]=a1g0[1];p[32]=a1g0[2];p[48]=a1g0[3];
        p = abase + ((ks*4 + 2+mt)*3 + 1)*256; p[0]=a1g1[0];p[16]=a1g1[1];p[32]=a1g1[2];p[48]=a1g1[3];
        p = abase + ((ks*4 + 2+mt)*3 + 2)*256; p[0]=a1g2[0];p[16]=a1g2[1];p[32]=a1g2[2];p[48]=a1g2[3];
      }
      __syncthreads();
      // 6. gates
      #pragma unroll
      for (int ei = 0; ei < 3; ++ei) {
        int e = tid + ei * 384;
        if (e < 1024) {
          int lrow = e >> 4, lcol = e & 15;
          int m4 = lrow >> 4, off = (lrow & 15) * 16 + lcol;
          float ghr = sGh[((0*4+m4)*3+0)*256+off] + sGh[((1*4+m4)*3+0)*256+off] + sGh[((2*4+m4)*3+0)*256+off];
          float ghz = sGh[((0*4+m4)*3+1)*256+off] + sGh[((1*4+m4)*3+1)*256+off] + sGh[((2*4+m4)*3+1)*256+off];
          float ghn = sGh[((0*4+m4)*3+2)*256+off] + sGh[((1*4+m4)*3+2)*256+off] + sGh[((2*4+m4)*3+2)*256+off];
          float gir = sGh[(36+0*4+m4)*256+off] + sGh[(36+1*4+m4)*256+off];
          float giz = sGh[(36+2*4+m4)*256+off] + sGh[(36+3*4+m4)*256+off];
          float gin = sGh[(36+4*4+m4)*256+off] + sGh[(36+5*4+m4)*256+off];
          float r = 1.f / (1.f + __expf(-(gir + ghr + sBias[lcol])));
          float z = 1.f / (1.f + __expf(-(giz + ghz + sBias[16 + lcol])));
          float npre = (gin + sBias[32 + lcol]) + r * (ghn + sBias[48 + lcol]);
          float n = 2.f / (1.f + __expf(-2.f * npre)) - 1.f;
          float hn = (1.f - z) * n + z * hown[ei];
          hown[ei] = hn;
          ((unsigned short*)sH)[e] = __bfloat16_as_ushort(__float2bfloat16(hn));
        }
      }
      __syncthreads();
      // 7. publish hbuf1[(t+1)&1] + flag
      if (tid < 128) {
        i32x4 hv = *(const i32x4*)(sH + (tid >> 1) * 32 + (tid & 1) * 16);
        stg_sc(hbuf1 + ((t + 1) & 1) * BH + (r0 + (tid >> 1)) * NH + c0 + (tid & 1) * 8, hv);
      }
      vm0_fence();
      if (tid == 0)
        __hip_atomic_store(flagL + cidx * 16, (unsigned int)(t + 2),
                           __ATOMIC_RELAXED, __HIP_MEMORY_SCOPE_AGENT);
    }
  }

  #pragma unroll
  for (int ei = 0; ei < 3; ++ei) {
    int e = tid + ei * 384;
    if (e < 1024) {
      int row = e >> 4, col = e & 15;
      houtl[(r0 + row) * NH + c0 + col] = hown[ei];
    }
  }
}

__global__ __launch_bounds__(256) void logits_kernel(
    const __hip_bfloat16* __restrict__ h1,   // hbuf1 slot 0 = h1(256)
    const float* __restrict__ fcW,
    const float* __restrict__ fcb,
    float* __restrict__ out)
{
  __shared__ float hrow[NH];
  int b = blockIdx.x, v = threadIdx.x;
  if (v < 128) {
    i32x4 hv;
    ldg_sc(hv, h1 + b * NH + v * 8);
    vm0_fence();
    use_dep(hv);
    short8 s = __builtin_bit_cast(short8, hv);
    #pragma unroll
    for (int j = 0; j < 8; ++j) {
      union { unsigned int i; float f; } c;
      c.i = ((unsigned int)(unsigned short)s[j]) << 16;
      hrow[v * 8 + j] = c.f;
    }
  }
  __syncthreads();
  float acc = fcb[v];
  for (int k = 0; k < NH; k += 4) {
    f4 wv = *(const f4*)(fcW + v * NH + k);
    #pragma unroll
    for (int j = 0; j < 4; ++j) acc += wv[j] * hrow[k + j];
  }
  out[b * NV + v] = acc;
}

extern "C" void kernel_launch(void* const* d_in, const int* in_sizes, int n_in,
                              void* d_out, int out_size, void* d_ws, size_t ws_size,
                              hipStream_t stream) {
  const int*   x    = (const int*)d_in[0];
  const float* h0   = (const float*)d_in[1];
  const float* emb  = (const float*)d_in[2];
  const float* Wih0 = (const float*)d_in[3];
  const float* Whh0 = (const float*)d_in[4];
  const float* bih0 = (const float*)d_in[5];
  const float* bhh0 = (const float*)d_in[6];
  const float* Wih1 = (const float*)d_in[7];
  const float* Whh1 = (const float*)d_in[8];
  const float* bih1 = (const float*)d_in[9];
  const float* bhh1 = (const float*)d_in[10];
  const float* fcW  = (const float*)d_in[11];
  const float* fcb  = (const float*)d_in[12];
  float* out = (float*)d_out;

  char* ws = (char*)d_ws;
  size_t off = 0;
  __hip_bfloat16* Ys    = (__hip_bfloat16*)ws;           off += (size_t)NT * BH * 2;   // 64MB
  __hip_bfloat16* hbuf1 = (__hip_bfloat16*)(ws + off);   off += (size_t)2 * BH * 2;
  __hip_bfloat16* embb  = (__hip_bfloat16*)(ws + off);   off += (size_t)NV * NE * 2;
  unsigned int*   flags = (unsigned int*)(ws + off);     off += 2 * 2 * 64 * 16 * 4;

  (void)hipMemsetAsync(flags, 0, 2 * 2 * 64 * 16 * 4, stream);
  embcvt_kernel<<<dim3(NV * NE / 256), dim3(256), 0, stream>>>(emb, embb);

  constexpr int lds = WHH_BYTES + GH_FLOATS * 4 + 64 * 4 + 2048;  // 162048
  (void)hipFuncSetAttribute(reinterpret_cast<const void*>(gru_fused),
                            hipFuncAttributeMaxDynamicSharedMemorySize, lds);

  gru_fused<<<dim3(256), dim3(384), lds, stream>>>(
      x, embb, Wih0, Whh0, bih0, bhh0, Wih1, Whh1, bih1, bhh1,
      h0, Ys, hbuf1, out + 32768, flags);
  logits_kernel<<<dim3(NB), dim3(256), 0, stream>>>(hbuf1, fcW, fcb, out);
}

// Round 13
// 4041.236 us; speedup vs baseline: 1.3759x; 1.3623x over previous
//
#include <hip/hip_runtime.h>
#include <hip/hip_bf16.h>

using bf16x8 = __attribute__((ext_vector_type(8))) __bf16;
using short8 = __attribute__((ext_vector_type(8))) short;
using f32x4  = __attribute__((ext_vector_type(4))) float;
using f4     = __attribute__((ext_vector_type(4))) float;
using i32x4  = __attribute__((ext_vector_type(4))) int;

constexpr int NB = 128;    // batch
constexpr int NT = 256;    // time
constexpr int NH = 1024;   // hidden
constexpr int NE = 256;    // embed
constexpr int NV = 256;    // vocab

constexpr int WHH_BYTES = 48 * 2048;    // 98304: 48 rows x 1024 bf16
constexpr int GH_FLOATS = 30 * 256;     // 18 hh tiles + 12 input tiles
constexpr int NBLK = 256;

// ---- cache-bypass (coherence-point) memory ops: no bulk wbl2/inv needed ----
__device__ __forceinline__ void ldg_sc(i32x4& d, const void* p) {
  asm volatile("global_load_dwordx4 %0, %1, off sc0 sc1" : "=v"(d) : "v"(p));
}
__device__ __forceinline__ void ldg_c(i32x4& d, const void* p) {   // cached path
  asm volatile("global_load_dwordx4 %0, %1, off" : "=v"(d) : "v"(p));
}
__device__ __forceinline__ void stg_sc(void* p, i32x4 v) {
  asm volatile("global_store_dwordx4 %0, %1, off sc0 sc1" :: "v"(p), "v"(v) : "memory");
}
__device__ __forceinline__ void vm0_fence() {
  asm volatile("s_waitcnt vmcnt(0)" ::: "memory");
}
__device__ __forceinline__ void use_dep(i32x4& d) {
  asm volatile("" : "+v"(d));
}

// 8 contiguous f32 -> bf16x8 (RNE)
__device__ __forceinline__ bf16x8 cvt8(const float* p) {
  short8 r;
  #pragma unroll
  for (int j = 0; j < 8; ++j)
    r[j] = (short)__bfloat16_as_ushort(__float2bfloat16(p[j]));
  return __builtin_bit_cast(bf16x8, r);
}

__global__ __launch_bounds__(256) void embcvt_kernel(const float* __restrict__ e,
                                                     __hip_bfloat16* __restrict__ o) {
  int i = blockIdx.x * 256 + threadIdx.x;
  o[i] = __float2bfloat16(e[i]);
}

// 256 WGs x 384 threads (R10 structure). WG owns h'[rb*32:+32, c0:+16].
// Wave wv=(mt,ks): hh GEMM = m-tile mt, K-slice ks, all 3 gates; input GEMM
// = gate ks, K-HALF mt, both m-tiles (16 frags, no spill).
// NEW (R13): LAYER==1 prefetches m-tile-0's y0 fragments ONE PERIOD AHEAD
// (y0 comes from the finished L0 dispatch -- no flag dependency). Issued
// after gates, latency hides under barrier+publish+flag RT; consumed at
// loop top as pure register compute before the poll.
template<int LAYER>
__global__ __launch_bounds__(384, 1) void gru_kernel(
    const int* __restrict__ x,
    const __hip_bfloat16* __restrict__ embb,
    const float* __restrict__ Wih,
    const float* __restrict__ Whh,
    const float* __restrict__ bih,
    const float* __restrict__ bhh,
    const float* __restrict__ h0,
    const __hip_bfloat16* __restrict__ yin,
    __hip_bfloat16* __restrict__ yout,
    __hip_bfloat16* __restrict__ hbuf,        // [2][128][1024]
    float* __restrict__ hout,
    unsigned int* __restrict__ flags)         // [4][64][16] uints
{
  extern __shared__ char smem[];
  char*  sWhh  = smem;
  float* sGh   = (float*)(smem + WHH_BYTES);
  float* sBias = sGh + GH_FLOATS;
  char*  sH    = (char*)(sBias + 64);         // 32x16 bf16 h' staging (1KB)

  const int tid  = threadIdx.x;
  const int lane = tid & 63;
  const int wv   = tid >> 6;
  const int mt   = wv & 1;
  const int ks   = wv >> 1;                   // K-slice / input gate, 0..2
  const int b    = blockIdx.x;
  const int rb   = (b >> 1) & 3;
  const int cidx = (b & 1) * 32 + (b >> 3);
  const int r0   = rb * 32;
  const int c0   = cidx * 16;
  unsigned int* pf = flags + rb * 64 * 16;
  const int slot = cidx;
  const int l16  = lane & 15;
  const int lk8  = (lane >> 4) * 8;

  // ---- stage W_hh slice swizzled (rows gate-major: gr>>4 = gate) ----
  for (int it = 0; it < 16; ++it) {
    int idx = it * 384 + tid;
    int gr = idx >> 7, kc = idx & 127;
    int grow = (gr >> 4) * NH + c0 + (gr & 15);
    short8 v = __builtin_bit_cast(short8, cvt8(Whh + grow * NH + kc * 8));
    *(short8*)(sWhh + ((gr * 2048 + kc * 16) ^ ((gr & 7) << 4))) = v;
  }
  if (tid < 16)       sBias[tid] = bih[c0 + tid] + bhh[c0 + tid];
  else if (tid < 32)  { int c = NH + c0 + tid - 16;   sBias[tid] = bih[c] + bhh[c]; }
  else if (tid < 48)  { int c = 2*NH + c0 + tid - 32; sBias[tid] = bih[c]; }
  else if (tid < 64)  { int c = 2*NH + c0 + tid - 48; sBias[tid] = bhh[c]; }

  // ---- W_ih VGPR fragments: gate ks, K-half mt (no spill) ----
  constexpr int KIN   = (LAYER == 0) ? NE : NH;
  constexpr int NFRAG = KIN / 64;             // L0: 4, L1: 16
  const int khalf = mt * (KIN / 2);
  bf16x8 wreg[NFRAG];
  #pragma unroll
  for (int kf = 0; kf < NFRAG; ++kf) {
    int grow = ks * NH + c0 + l16;
    wreg[kf] = cvt8(Wih + grow * KIN + khalf + kf * 32 + lk8);
  }

  // ---- init h0 -> regs + sH -> staged sc publish + flag=1 ----
  float hown[2] = {0.f, 0.f};
  #pragma unroll
  for (int ei = 0; ei < 2; ++ei) {
    int e = tid + ei * 384;
    if (e < 512) {
      float hv = h0[(r0 + (e >> 4)) * NH + c0 + (e & 15)];
      hown[ei] = hv;
      ((unsigned short*)sH)[e] = __bfloat16_as_ushort(__float2bfloat16(hv));
    }
  }
  __syncthreads();
  if (tid < 64) {
    i32x4 hv = *(const i32x4*)(sH + (tid >> 1) * 32 + (tid & 1) * 16);
    stg_sc(hbuf + (r0 + (tid >> 1)) * NH + c0 + (tid & 1) * 8, hv);
    vm0_fence();
    if (tid == 0)
      __hip_atomic_store(pf + slot * 16, 1u, __ATOMIC_RELAXED,
                         __HIP_MEMORY_SCOPE_AGENT);
  }

  // ---- L1 prologue: prefetch m-tile-0 input fragments for t=0 ----
  i32x4 pf0[(LAYER == 1) ? 16 : 1];
  if constexpr (LAYER == 1) {
    const __hip_bfloat16* yp = yin + ((r0 + l16) * NT + 0) * NH + khalf + lk8;
    #pragma unroll
    for (int kf = 0; kf < 16; ++kf) ldg_c(pf0[kf], yp + kf * 32);
    vm0_fence();
    #pragma unroll
    for (int kf = 0; kf < 16; ++kf) use_dep(pf0[kf]);
  }

  // ---- time loop ----
  for (int t = 0; t < NT; ++t) {
    const __hip_bfloat16* rbuf = hbuf + (t & 1) * (NB * NH);
    __hip_bfloat16* wbuf = hbuf + ((t + 1) & 1) * (NB * NH);
    const int arow = r0 + mt * 16 + l16;
    const int bxor = (l16 & 7) << 4;
    float* abase = sGh + (lane >> 4) * 64 + l16;

    // ---- 1a. input GEMM m-tile 0 (L0: cached emb; L1: prefetched regs) ----
    f32x4 ai0 = {0.f,0.f,0.f,0.f}, ai1 = {0.f,0.f,0.f,0.f};
    const __hip_bfloat16 *xp1;
    if constexpr (LAYER == 0) {
      const __hip_bfloat16* xp0 = embb + x[(r0 + l16) * NT + t] * NE + khalf + lk8;
      xp1 = embb + x[(r0 + 16 + l16) * NT + t] * NE + khalf + lk8;
      #pragma unroll
      for (int kf = 0; kf < NFRAG; ++kf) {
        bf16x8 a = __builtin_bit_cast(bf16x8, *(const short8*)(xp0 + kf * 32));
        ai0 = __builtin_amdgcn_mfma_f32_16x16x32_bf16(a, wreg[kf], ai0, 0, 0, 0);
      }
    } else {
      // data already in registers (prefetched last period; vmcnt drained by
      // the publish fence for wave0 and waited below for others)
      vm0_fence();
      #pragma unroll
      for (int kf = 0; kf < 16; ++kf) use_dep(pf0[kf]);
      xp1 = yin + ((r0 + 16 + l16) * NT + t) * NH + khalf + lk8;
      #pragma unroll
      for (int kf = 0; kf < NFRAG; ++kf) {
        bf16x8 a = __builtin_bit_cast(bf16x8, pf0[kf]);
        ai0 = __builtin_amdgcn_mfma_f32_16x16x32_bf16(a, wreg[kf], ai0, 0, 0, 0);
      }
    }

    // ---- 2. wait for all producers of h(t) (wave0 polls padded flags) ----
    {
      unsigned int ep = (unsigned int)(t + 1);
      if (tid < 64) {
        const unsigned int* f = pf + tid * 16;
        while (__hip_atomic_load(f, __ATOMIC_RELAXED,
                                 __HIP_MEMORY_SCOPE_AGENT) < ep)
          __builtin_amdgcn_s_sleep(1);
      }
      __syncthreads();
    }

    // ---- 3a. issue ALL A sc-loads for this wave's k-slice ----
    const int nk = (ks < 2) ? 11 : 10;
    const __hip_bfloat16* aptr = rbuf + arow * NH + lk8;
    i32x4 fr[11];
    #pragma unroll
    for (int i = 0; i < 11; ++i)
      if (i < nk) ldg_sc(fr[i], aptr + (ks + 3 * i) * 32);

    // ---- 1b. input GEMM m-tile 1 (hides A-load round trip) ----
    #pragma unroll
    for (int kf = 0; kf < NFRAG; ++kf) {
      bf16x8 a = __builtin_bit_cast(bf16x8, *(const short8*)(xp1 + kf * 32));
      ai1 = __builtin_amdgcn_mfma_f32_16x16x32_bf16(a, wreg[kf], ai1, 0, 0, 0);
    }
    {   // input partials -> tiles 18 + (ks*2 + mt)*2 + m
      float* pi0 = abase + (18 + (ks * 2 + mt) * 2 + 0) * 256;
      float* pi1 = abase + (18 + (ks * 2 + mt) * 2 + 1) * 256;
      pi0[0]=ai0[0]; pi0[16]=ai0[1]; pi0[32]=ai0[2]; pi0[48]=ai0[3];
      pi1[0]=ai1[0]; pi1[16]=ai1[1]; pi1[32]=ai1[2]; pi1[48]=ai1[3];
    }

    // ---- 3b. W_hh MFMAs: A from regs, all 3 gates per chunk ----
    vm0_fence();
    #pragma unroll
    for (int i = 0; i < 11; ++i)
      if (i < nk) use_dep(fr[i]);
    {
      f32x4 ah0 = {0.f,0.f,0.f,0.f}, ah1 = {0.f,0.f,0.f,0.f}, ah2 = {0.f,0.f,0.f,0.f};
      const int bb0 = (l16)      * 2048 + lk8 * 2;
      const int bb1 = (16 + l16) * 2048 + lk8 * 2;
      const int bb2 = (32 + l16) * 2048 + lk8 * 2;
      #pragma unroll
      for (int i = 0; i < 11; ++i) {
        if (i < nk) {
          int kk = ks + 3 * i;
          bf16x8 a = __builtin_bit_cast(bf16x8, fr[i]);
          bf16x8 b0 = __builtin_bit_cast(bf16x8,
              *(const short8*)(sWhh + ((bb0 + kk * 64) ^ bxor)));
          ah0 = __builtin_amdgcn_mfma_f32_16x16x32_bf16(a, b0, ah0, 0, 0, 0);
          bf16x8 b1 = __builtin_bit_cast(bf16x8,
              *(const short8*)(sWhh + ((bb1 + kk * 64) ^ bxor)));
          ah1 = __builtin_amdgcn_mfma_f32_16x16x32_bf16(a, b1, ah1, 0, 0, 0);
          bf16x8 b2 = __builtin_bit_cast(bf16x8,
              *(const short8*)(sWhh + ((bb2 + kk * 64) ^ bxor)));
          ah2 = __builtin_amdgcn_mfma_f32_16x16x32_bf16(a, b2, ah2, 0, 0, 0);
        }
      }
      // hh partials -> disjoint tiles [ks*6 + mt*3 + g]
      float* p0 = abase + (ks * 6 + mt * 3 + 0) * 256;
      float* p1 = abase + (ks * 6 + mt * 3 + 1) * 256;
      float* p2 = abase + (ks * 6 + mt * 3 + 2) * 256;
      p0[0]=ah0[0]; p0[16]=ah0[1]; p0[32]=ah0[2]; p0[48]=ah0[3];
      p1[0]=ah1[0]; p1[16]=ah1[1]; p1[32]=ah1[2]; p1[48]=ah1[3];
      p2[0]=ah2[0]; p2[16]=ah2[1]; p2[32]=ah2[2]; p2[48]=ah2[3];
    }
    __syncthreads();

    // ---- 4. gates: sum partials (3 ks-slices hh, 2 K-halves input) ----
    #pragma unroll
    for (int ei = 0; ei < 2; ++ei) {
      int e = tid + ei * 384;
      if (e < 512) {
        int lrow = e >> 4, lcol = e & 15;
        int m2 = lrow >> 4, off = (lrow & 15) * 16 + lcol;
        float ghr = sGh[(0*6 + m2*3 + 0) * 256 + off]
                  + sGh[(1*6 + m2*3 + 0) * 256 + off]
                  + sGh[(2*6 + m2*3 + 0) * 256 + off];
        float ghz = sGh[(0*6 + m2*3 + 1) * 256 + off]
                  + sGh[(1*6 + m2*3 + 1) * 256 + off]
                  + sGh[(2*6 + m2*3 + 1) * 256 + off];
        float ghn = sGh[(0*6 + m2*3 + 2) * 256 + off]
                  + sGh[(1*6 + m2*3 + 2) * 256 + off]
                  + sGh[(2*6 + m2*3 + 2) * 256 + off];
        float gir = sGh[(18 + (0*2+0)*2 + m2) * 256 + off]
                  + sGh[(18 + (0*2+1)*2 + m2) * 256 + off];
        float giz = sGh[(18 + (1*2+0)*2 + m2) * 256 + off]
                  + sGh[(18 + (1*2+1)*2 + m2) * 256 + off];
        float gin = sGh[(18 + (2*2+0)*2 + m2) * 256 + off]
                  + sGh[(18 + (2*2+1)*2 + m2) * 256 + off];
        float r = 1.f / (1.f + __expf(-(gir + ghr + sBias[lcol])));
        float z = 1.f / (1.f + __expf(-(giz + ghz + sBias[16 + lcol])));
        float npre = (gin + sBias[32 + lcol]) + r * (ghn + sBias[48 + lcol]);
        float n = 2.f / (1.f + __expf(-2.f * npre)) - 1.f;   // tanh, inf-safe
        float hn = (1.f - z) * n + z * hown[ei];
        hown[ei] = hn;
        __hip_bfloat16 hb = __float2bfloat16(hn);
        ((unsigned short*)sH)[e] = __bfloat16_as_ushort(hb);
        if constexpr (LAYER == 0)
          yout[((r0 + lrow) * NT + t) * NH + c0 + lcol] = hb;
      }
    }

    // ---- 4b. L1: prefetch next period's m-tile-0 input fragments ----
    if constexpr (LAYER == 1) {
      int tn = (t + 1 < NT) ? (t + 1) : (NT - 1);
      const __hip_bfloat16* yp = yin + ((r0 + l16) * NT + tn) * NH + khalf + lk8;
      #pragma unroll
      for (int kf = 0; kf < 16; ++kf) ldg_c(pf0[kf], yp + kf * 32);
    }

    // ---- 5. publish h' (staged 16B sc-stores) + flag epoch t+2 ----
    __syncthreads();
    if (tid < 64) {
      i32x4 hv = *(const i32x4*)(sH + (tid >> 1) * 32 + (tid & 1) * 16);
      stg_sc(wbuf + (r0 + (tid >> 1)) * NH + c0 + (tid & 1) * 8, hv);
      vm0_fence();
      if (tid == 0)
        __hip_atomic_store(pf + slot * 16, (unsigned int)(t + 2),
                           __ATOMIC_RELAXED, __HIP_MEMORY_SCOPE_AGENT);
    }
  }

  #pragma unroll
  for (int ei = 0; ei < 2; ++ei) {
    int e = tid + ei * 384;
    if (e < 512) {
      int lrow = e >> 4, lcol = e & 15;
      hout[(r0 + lrow) * NH + c0 + lcol] = hown[ei];
    }
  }
}

__global__ __launch_bounds__(256) void logits_kernel(
    const __hip_bfloat16* __restrict__ h1,
    const float* __restrict__ fcW,
    const float* __restrict__ fcb,
    float* __restrict__ out)
{
  __shared__ float hrow[NH];
  int b = blockIdx.x, v = threadIdx.x;
  if (v < 128) {
    i32x4 hv;
    ldg_sc(hv, h1 + b * NH + v * 8);
    vm0_fence();
    use_dep(hv);
    short8 s = __builtin_bit_cast(short8, hv);
    #pragma unroll
    for (int j = 0; j < 8; ++j) {
      union { unsigned int i; float f; } c;
      c.i = ((unsigned int)(unsigned short)s[j]) << 16;
      hrow[v * 8 + j] = c.f;
    }
  }
  __syncthreads();
  float acc = fcb[v];
  for (int k = 0; k < NH; k += 4) {
    f4 wv = *(const f4*)(fcW + v * NH + k);
    #pragma unroll
    for (int j = 0; j < 4; ++j) acc += wv[j] * hrow[k + j];
  }
  out[b * NV + v] = acc;
}

extern "C" void kernel_launch(void* const* d_in, const int* in_sizes, int n_in,
                              void* d_out, int out_size, void* d_ws, size_t ws_size,
                              hipStream_t stream) {
  const int*   x    = (const int*)d_in[0];
  const float* h0   = (const float*)d_in[1];
  const float* emb  = (const float*)d_in[2];
  const float* Wih0 = (const float*)d_in[3];
  const float* Whh0 = (const float*)d_in[4];
  const float* bih0 = (const float*)d_in[5];
  const float* bhh0 = (const float*)d_in[6];
  const float* Wih1 = (const float*)d_in[7];
  const float* Whh1 = (const float*)d_in[8];
  const float* bih1 = (const float*)d_in[9];
  const float* bhh1 = (const float*)d_in[10];
  const float* fcW  = (const float*)d_in[11];
  const float* fcb  = (const float*)d_in[12];
  float* out = (float*)d_out;

  char* ws = (char*)d_ws;
  size_t off = 0;
  __hip_bfloat16* y0   = (__hip_bfloat16*)ws;            off += (size_t)NB * NT * NH * 2;
  __hip_bfloat16* hbuf = (__hip_bfloat16*)(ws + off);    off += (size_t)2 * NB * NH * 2;
  __hip_bfloat16* embb = (__hip_bfloat16*)(ws + off);    off += (size_t)NV * NE * 2;
  unsigned int*  flags0 = (unsigned int*)(ws + off);     off += 4 * 64 * 16 * 4;
  unsigned int*  flags1 = (unsigned int*)(ws + off);     off += 4 * 64 * 16 * 4;

  (void)hipMemsetAsync(flags0, 0, 2 * 4 * 64 * 16 * 4, stream);
  embcvt_kernel<<<dim3(NV * NE / 256), dim3(256), 0, stream>>>(emb, embb);

  constexpr int lds = WHH_BYTES + GH_FLOATS * 4 + 64 * 4 + 1024;  // 130304
  (void)hipFuncSetAttribute(reinterpret_cast<const void*>(gru_kernel<0>),
                            hipFuncAttributeMaxDynamicSharedMemorySize, lds);
  (void)hipFuncSetAttribute(reinterpret_cast<const void*>(gru_kernel<1>),
                            hipFuncAttributeMaxDynamicSharedMemorySize, lds);

  gru_kernel<0><<<dim3(NBLK), dim3(384), lds, stream>>>(
      x, embb, Wih0, Whh0, bih0, bhh0, h0, y0, y0, hbuf, out + 32768, flags0);
  gru_kernel<1><<<dim3(NBLK), dim3(384), lds, stream>>>(
      x, embb, Wih1, Whh1, bih1, bhh1, h0 + NB * NH, y0, y0, hbuf,
      out + 32768 + NB * NH, flags1);
  logits_kernel<<<dim3(NB), dim3(256), 0, stream>>>(hbuf, fcW, fcb, out);
}

// Round 14
// 3963.300 us; speedup vs baseline: 1.4030x; 1.0197x over previous
//
#include <hip/hip_runtime.h>
#include <hip/hip_bf16.h>

using bf16x8 = __attribute__((ext_vector_type(8))) __bf16;
using short8 = __attribute__((ext_vector_type(8))) short;
using f32x4  = __attribute__((ext_vector_type(4))) float;
using f4     = __attribute__((ext_vector_type(4))) float;
using i32x4  = __attribute__((ext_vector_type(4))) int;

constexpr int NB = 128;    // batch
constexpr int NT = 256;    // time
constexpr int NH = 1024;   // hidden
constexpr int NE = 256;    // embed
constexpr int NV = 256;    // vocab

constexpr int WHH_BYTES = 48 * 2048;    // 98304: 48 rows x 1024 bf16
constexpr int GH_FLOATS = 30 * 256;     // 18 hh tiles + 12 input tiles
constexpr int NBLK = 256;

// ---- cache-bypass (coherence-point) memory ops: no bulk wbl2/inv needed ----
__device__ __forceinline__ void ldg_sc(i32x4& d, const void* p) {
  asm volatile("global_load_dwordx4 %0, %1, off sc0 sc1" : "=v"(d) : "v"(p));
}
__device__ __forceinline__ void ldg_c(i32x4& d, const void* p) {   // cached path
  asm volatile("global_load_dwordx4 %0, %1, off" : "=v"(d) : "v"(p));
}
__device__ __forceinline__ void stg_sc(void* p, i32x4 v) {
  asm volatile("global_store_dwordx4 %0, %1, off sc0 sc1" :: "v"(p), "v"(v) : "memory");
}
__device__ __forceinline__ void vm0_fence() {
  asm volatile("s_waitcnt vmcnt(0)" ::: "memory");
}
__device__ __forceinline__ void use_dep(i32x4& d) {
  asm volatile("" : "+v"(d));
}

// 8 contiguous f32 -> bf16x8 (RNE)
__device__ __forceinline__ bf16x8 cvt8(const float* p) {
  short8 r;
  #pragma unroll
  for (int j = 0; j < 8; ++j)
    r[j] = (short)__bfloat16_as_ushort(__float2bfloat16(p[j]));
  return __builtin_bit_cast(bf16x8, r);
}

__global__ __launch_bounds__(256) void embcvt_kernel(const float* __restrict__ e,
                                                     __hip_bfloat16* __restrict__ o) {
  int i = blockIdx.x * 256 + threadIdx.x;
  o[i] = __float2bfloat16(e[i]);
}

// 256 WGs x 384 threads (R10 structure). WG owns h'[rb*32:+32, c0:+16].
// Wave wv=(mt,ks): hh GEMM = m-tile mt, K-slice ks, all 3 gates; input GEMM
// = gate ks, K-HALF mt, both m-tiles (16 frags, no spill).
// R14: y0 is TIME-MAJOR [T][B][H], written by WAVE 1 as staged 16B vector
// stores from sH (parallel with wave0's publish, OFF the flag chain).
// R13's L0 was the slow layer: 512 scattered 2B y0 stores drained by the
// pre-flag vmcnt(0) every step. L1 reads/prefetches y0 t-major.
template<int LAYER>
__global__ __launch_bounds__(384, 1) void gru_kernel(
    const int* __restrict__ x,
    const __hip_bfloat16* __restrict__ embb,
    const float* __restrict__ Wih,
    const float* __restrict__ Whh,
    const float* __restrict__ bih,
    const float* __restrict__ bhh,
    const float* __restrict__ h0,
    const __hip_bfloat16* __restrict__ yin,   // [T][B][H] (layer1 input)
    __hip_bfloat16* __restrict__ yout,        // [T][B][H] (layer0 output)
    __hip_bfloat16* __restrict__ hbuf,        // [2][128][1024]
    float* __restrict__ hout,
    unsigned int* __restrict__ flags)         // [4][64][16] uints
{
  extern __shared__ char smem[];
  char*  sWhh  = smem;
  float* sGh   = (float*)(smem + WHH_BYTES);
  float* sBias = sGh + GH_FLOATS;
  char*  sH    = (char*)(sBias + 64);         // 32x16 bf16 h' staging (1KB)

  const int tid  = threadIdx.x;
  const int lane = tid & 63;
  const int wv   = tid >> 6;
  const int mt   = wv & 1;
  const int ks   = wv >> 1;                   // K-slice / input gate, 0..2
  const int b    = blockIdx.x;
  const int rb   = (b >> 1) & 3;
  const int cidx = (b & 1) * 32 + (b >> 3);
  const int r0   = rb * 32;
  const int c0   = cidx * 16;
  unsigned int* pf = flags + rb * 64 * 16;
  const int slot = cidx;
  const int l16  = lane & 15;
  const int lk8  = (lane >> 4) * 8;

  // ---- stage W_hh slice swizzled (rows gate-major: gr>>4 = gate) ----
  for (int it = 0; it < 16; ++it) {
    int idx = it * 384 + tid;
    int gr = idx >> 7, kc = idx & 127;
    int grow = (gr >> 4) * NH + c0 + (gr & 15);
    short8 v = __builtin_bit_cast(short8, cvt8(Whh + grow * NH + kc * 8));
    *(short8*)(sWhh + ((gr * 2048 + kc * 16) ^ ((gr & 7) << 4))) = v;
  }
  if (tid < 16)       sBias[tid] = bih[c0 + tid] + bhh[c0 + tid];
  else if (tid < 32)  { int c = NH + c0 + tid - 16;   sBias[tid] = bih[c] + bhh[c]; }
  else if (tid < 48)  { int c = 2*NH + c0 + tid - 32; sBias[tid] = bih[c]; }
  else if (tid < 64)  { int c = 2*NH + c0 + tid - 48; sBias[tid] = bhh[c]; }

  // ---- W_ih VGPR fragments: gate ks, K-half mt (no spill) ----
  constexpr int KIN   = (LAYER == 0) ? NE : NH;
  constexpr int NFRAG = KIN / 64;             // L0: 4, L1: 16
  const int khalf = mt * (KIN / 2);
  bf16x8 wreg[NFRAG];
  #pragma unroll
  for (int kf = 0; kf < NFRAG; ++kf) {
    int grow = ks * NH + c0 + l16;
    wreg[kf] = cvt8(Wih + grow * KIN + khalf + kf * 32 + lk8);
  }

  // ---- init h0 -> regs + sH -> staged sc publish + flag=1 ----
  float hown[2] = {0.f, 0.f};
  #pragma unroll
  for (int ei = 0; ei < 2; ++ei) {
    int e = tid + ei * 384;
    if (e < 512) {
      float hv = h0[(r0 + (e >> 4)) * NH + c0 + (e & 15)];
      hown[ei] = hv;
      ((unsigned short*)sH)[e] = __bfloat16_as_ushort(__float2bfloat16(hv));
    }
  }
  __syncthreads();
  if (tid < 64) {
    i32x4 hv = *(const i32x4*)(sH + (tid >> 1) * 32 + (tid & 1) * 16);
    stg_sc(hbuf + (r0 + (tid >> 1)) * NH + c0 + (tid & 1) * 8, hv);
    vm0_fence();
    if (tid == 0)
      __hip_atomic_store(pf + slot * 16, 1u, __ATOMIC_RELAXED,
                         __HIP_MEMORY_SCOPE_AGENT);
  }

  // ---- L1 prologue: prefetch m-tile-0 input fragments for t=0 ----
  i32x4 pf0[(LAYER == 1) ? 16 : 1];
  if constexpr (LAYER == 1) {
    const __hip_bfloat16* yp = yin + ((size_t)0 * NB + (r0 + l16)) * NH + khalf + lk8;
    #pragma unroll
    for (int kf = 0; kf < 16; ++kf) ldg_c(pf0[kf], yp + kf * 32);
    vm0_fence();
    #pragma unroll
    for (int kf = 0; kf < 16; ++kf) use_dep(pf0[kf]);
  }

  // ---- time loop ----
  for (int t = 0; t < NT; ++t) {
    const __hip_bfloat16* rbuf = hbuf + (t & 1) * (NB * NH);
    __hip_bfloat16* wbuf = hbuf + ((t + 1) & 1) * (NB * NH);
    const int arow = r0 + mt * 16 + l16;
    const int bxor = (l16 & 7) << 4;
    float* abase = sGh + (lane >> 4) * 64 + l16;

    // ---- 1a. input GEMM m-tile 0 (L0: cached emb; L1: prefetched regs) ----
    f32x4 ai0 = {0.f,0.f,0.f,0.f}, ai1 = {0.f,0.f,0.f,0.f};
    const __hip_bfloat16 *xp1;
    if constexpr (LAYER == 0) {
      const __hip_bfloat16* xp0 = embb + x[(r0 + l16) * NT + t] * NE + khalf + lk8;
      xp1 = embb + x[(r0 + 16 + l16) * NT + t] * NE + khalf + lk8;
      #pragma unroll
      for (int kf = 0; kf < NFRAG; ++kf) {
        bf16x8 a = __builtin_bit_cast(bf16x8, *(const short8*)(xp0 + kf * 32));
        ai0 = __builtin_amdgcn_mfma_f32_16x16x32_bf16(a, wreg[kf], ai0, 0, 0, 0);
      }
    } else {
      vm0_fence();
      #pragma unroll
      for (int kf = 0; kf < 16; ++kf) use_dep(pf0[kf]);
      xp1 = yin + ((size_t)t * NB + (r0 + 16 + l16)) * NH + khalf + lk8;
      #pragma unroll
      for (int kf = 0; kf < NFRAG; ++kf) {
        bf16x8 a = __builtin_bit_cast(bf16x8, pf0[kf]);
        ai0 = __builtin_amdgcn_mfma_f32_16x16x32_bf16(a, wreg[kf], ai0, 0, 0, 0);
      }
    }

    // ---- 2. wait for all producers of h(t) (wave0 polls padded flags) ----
    {
      unsigned int ep = (unsigned int)(t + 1);
      if (tid < 64) {
        const unsigned int* f = pf + tid * 16;
        while (__hip_atomic_load(f, __ATOMIC_RELAXED,
                                 __HIP_MEMORY_SCOPE_AGENT) < ep)
          __builtin_amdgcn_s_sleep(1);
      }
      __syncthreads();
    }

    // ---- 3a. issue ALL A sc-loads for this wave's k-slice ----
    const int nk = (ks < 2) ? 11 : 10;
    const __hip_bfloat16* aptr = rbuf + arow * NH + lk8;
    i32x4 fr[11];
    #pragma unroll
    for (int i = 0; i < 11; ++i)
      if (i < nk) ldg_sc(fr[i], aptr + (ks + 3 * i) * 32);

    // ---- 1b. input GEMM m-tile 1 (hides A-load round trip) ----
    #pragma unroll
    for (int kf = 0; kf < NFRAG; ++kf) {
      bf16x8 a = __builtin_bit_cast(bf16x8, *(const short8*)(xp1 + kf * 32));
      ai1 = __builtin_amdgcn_mfma_f32_16x16x32_bf16(a, wreg[kf], ai1, 0, 0, 0);
    }
    {   // input partials -> tiles 18 + (ks*2 + mt)*2 + m
      float* pi0 = abase + (18 + (ks * 2 + mt) * 2 + 0) * 256;
      float* pi1 = abase + (18 + (ks * 2 + mt) * 2 + 1) * 256;
      pi0[0]=ai0[0]; pi0[16]=ai0[1]; pi0[32]=ai0[2]; pi0[48]=ai0[3];
      pi1[0]=ai1[0]; pi1[16]=ai1[1]; pi1[32]=ai1[2]; pi1[48]=ai1[3];
    }

    // ---- 3b. W_hh MFMAs: A from regs, all 3 gates per chunk ----
    vm0_fence();
    #pragma unroll
    for (int i = 0; i < 11; ++i)
      if (i < nk) use_dep(fr[i]);
    {
      f32x4 ah0 = {0.f,0.f,0.f,0.f}, ah1 = {0.f,0.f,0.f,0.f}, ah2 = {0.f,0.f,0.f,0.f};
      const int bb0 = (l16)      * 2048 + lk8 * 2;
      const int bb1 = (16 + l16) * 2048 + lk8 * 2;
      const int bb2 = (32 + l16) * 2048 + lk8 * 2;
      #pragma unroll
      for (int i = 0; i < 11; ++i) {
        if (i < nk) {
          int kk = ks + 3 * i;
          bf16x8 a = __builtin_bit_cast(bf16x8, fr[i]);
          bf16x8 b0 = __builtin_bit_cast(bf16x8,
              *(const short8*)(sWhh + ((bb0 + kk * 64) ^ bxor)));
          ah0 = __builtin_amdgcn_mfma_f32_16x16x32_bf16(a, b0, ah0, 0, 0, 0);
          bf16x8 b1 = __builtin_bit_cast(bf16x8,
              *(const short8*)(sWhh + ((bb1 + kk * 64) ^ bxor)));
          ah1 = __builtin_amdgcn_mfma_f32_16x16x32_bf16(a, b1, ah1, 0, 0, 0);
          bf16x8 b2 = __builtin_bit_cast(bf16x8,
              *(const short8*)(sWhh + ((bb2 + kk * 64) ^ bxor)));
          ah2 = __builtin_amdgcn_mfma_f32_16x16x32_bf16(a, b2, ah2, 0, 0, 0);
        }
      }
      // hh partials -> disjoint tiles [ks*6 + mt*3 + g]
      float* p0 = abase + (ks * 6 + mt * 3 + 0) * 256;
      float* p1 = abase + (ks * 6 + mt * 3 + 1) * 256;
      float* p2 = abase + (ks * 6 + mt * 3 + 2) * 256;
      p0[0]=ah0[0]; p0[16]=ah0[1]; p0[32]=ah0[2]; p0[48]=ah0[3];
      p1[0]=ah1[0]; p1[16]=ah1[1]; p1[32]=ah1[2]; p1[48]=ah1[3];
      p2[0]=ah2[0]; p2[16]=ah2[1]; p2[32]=ah2[2]; p2[48]=ah2[3];
    }
    __syncthreads();

    // ---- 4. gates: sum partials; h' -> sH only (no global stores here) ----
    #pragma unroll
    for (int ei = 0; ei < 2; ++ei) {
      int e = tid + ei * 384;
      if (e < 512) {
        int lrow = e >> 4, lcol = e & 15;
        int m2 = lrow >> 4, off = (lrow & 15) * 16 + lcol;
        float ghr = sGh[(0*6 + m2*3 + 0) * 256 + off]
                  + sGh[(1*6 + m2*3 + 0) * 256 + off]
                  + sGh[(2*6 + m2*3 + 0) * 256 + off];
        float ghz = sGh[(0*6 + m2*3 + 1) * 256 + off]
                  + sGh[(1*6 + m2*3 + 1) * 256 + off]
                  + sGh[(2*6 + m2*3 + 1) * 256 + off];
        float ghn = sGh[(0*6 + m2*3 + 2) * 256 + off]
                  + sGh[(1*6 + m2*3 + 2) * 256 + off]
                  + sGh[(2*6 + m2*3 + 2) * 256 + off];
        float gir = sGh[(18 + (0*2+0)*2 + m2) * 256 + off]
                  + sGh[(18 + (0*2+1)*2 + m2) * 256 + off];
        float giz = sGh[(18 + (1*2+0)*2 + m2) * 256 + off]
                  + sGh[(18 + (1*2+1)*2 + m2) * 256 + off];
        float gin = sGh[(18 + (2*2+0)*2 + m2) * 256 + off]
                  + sGh[(18 + (2*2+1)*2 + m2) * 256 + off];
        float r = 1.f / (1.f + __expf(-(gir + ghr + sBias[lcol])));
        float z = 1.f / (1.f + __expf(-(giz + ghz + sBias[16 + lcol])));
        float npre = (gin + sBias[32 + lcol]) + r * (ghn + sBias[48 + lcol]);
        float n = 2.f / (1.f + __expf(-2.f * npre)) - 1.f;   // tanh, inf-safe
        float hn = (1.f - z) * n + z * hown[ei];
        hown[ei] = hn;
        ((unsigned short*)sH)[e] = __bfloat16_as_ushort(__float2bfloat16(hn));
      }
    }

    // ---- 4b. L1: prefetch next period's m-tile-0 input fragments ----
    if constexpr (LAYER == 1) {
      int tn = (t + 1 < NT) ? (t + 1) : (NT - 1);
      const __hip_bfloat16* yp = yin + ((size_t)tn * NB + (r0 + l16)) * NH + khalf + lk8;
      #pragma unroll
      for (int kf = 0; kf < 16; ++kf) ldg_c(pf0[kf], yp + kf * 32);
    }

    // ---- 5. publish h' (wave0, sc) + flag; wave1 stores y0 (off-chain) ----
    __syncthreads();
    if constexpr (LAYER == 0) {
      if (tid >= 64 && tid < 128) {
        int l = tid & 63;
        i32x4 hv = *(const i32x4*)(sH + (l >> 1) * 32 + (l & 1) * 16);
        *(i32x4*)(yout + ((size_t)t * NB + (r0 + (l >> 1))) * NH + c0 + (l & 1) * 8) = hv;
      }
    }
    if (tid < 64) {
      i32x4 hv = *(const i32x4*)(sH + (tid >> 1) * 32 + (tid & 1) * 16);
      stg_sc(wbuf + (r0 + (tid >> 1)) * NH + c0 + (tid & 1) * 8, hv);
      vm0_fence();
      if (tid == 0)
        __hip_atomic_store(pf + slot * 16, (unsigned int)(t + 2),
                           __ATOMIC_RELAXED, __HIP_MEMORY_SCOPE_AGENT);
    }
  }

  #pragma unroll
  for (int ei = 0; ei < 2; ++ei) {
    int e = tid + ei * 384;
    if (e < 512) {
      int lrow = e >> 4, lcol = e & 15;
      hout[(r0 + lrow) * NH + c0 + lcol] = hown[ei];
    }
  }
}

__global__ __launch_bounds__(256) void logits_kernel(
    const __hip_bfloat16* __restrict__ h1,
    const float* __restrict__ fcW,
    const float* __restrict__ fcb,
    float* __restrict__ out)
{
  __shared__ float hrow[NH];
  int b = blockIdx.x, v = threadIdx.x;
  if (v < 128) {
    i32x4 hv;
    ldg_sc(hv, h1 + b * NH + v * 8);
    vm0_fence();
    use_dep(hv);
    short8 s = __builtin_bit_cast(short8, hv);
    #pragma unroll
    for (int j = 0; j < 8; ++j) {
      union { unsigned int i; float f; } c;
      c.i = ((unsigned int)(unsigned short)s[j]) << 16;
      hrow[v * 8 + j] = c.f;
    }
  }
  __syncthreads();
  float acc = fcb[v];
  for (int k = 0; k < NH; k += 4) {
    f4 wv = *(const f4*)(fcW + v * NH + k);
    #pragma unroll
    for (int j = 0; j < 4; ++j) acc += wv[j] * hrow[k + j];
  }
  out[b * NV + v] = acc;
}

extern "C" void kernel_launch(void* const* d_in, const int* in_sizes, int n_in,
                              void* d_out, int out_size, void* d_ws, size_t ws_size,
                              hipStream_t stream) {
  const int*   x    = (const int*)d_in[0];
  const float* h0   = (const float*)d_in[1];
  const float* emb  = (const float*)d_in[2];
  const float* Wih0 = (const float*)d_in[3];
  const float* Whh0 = (const float*)d_in[4];
  const float* bih0 = (const float*)d_in[5];
  const float* bhh0 = (const float*)d_in[6];
  const float* Wih1 = (const float*)d_in[7];
  const float* Whh1 = (const float*)d_in[8];
  const float* bih1 = (const float*)d_in[9];
  const float* bhh1 = (const float*)d_in[10];
  const float* fcW  = (const float*)d_in[11];
  const float* fcb  = (const float*)d_in[12];
  float* out = (float*)d_out;

  char* ws = (char*)d_ws;
  size_t off = 0;
  __hip_bfloat16* y0   = (__hip_bfloat16*)ws;            off += (size_t)NB * NT * NH * 2;  // [T][B][H]
  __hip_bfloat16* hbuf = (__hip_bfloat16*)(ws + off);    off += (size_t)2 * NB * NH * 2;
  __hip_bfloat16* embb = (__hip_bfloat16*)(ws + off);    off += (size_t)NV * NE * 2;
  unsigned int*  flags0 = (unsigned int*)(ws + off);     off += 4 * 64 * 16 * 4;
  unsigned int*  flags1 = (unsigned int*)(ws + off);     off += 4 * 64 * 16 * 4;

  (void)hipMemsetAsync(flags0, 0, 2 * 4 * 64 * 16 * 4, stream);
  embcvt_kernel<<<dim3(NV * NE / 256), dim3(256), 0, stream>>>(emb, embb);

  constexpr int lds = WHH_BYTES + GH_FLOATS * 4 + 64 * 4 + 1024;  // 130304
  (void)hipFuncSetAttribute(reinterpret_cast<const void*>(gru_kernel<0>),
                            hipFuncAttributeMaxDynamicSharedMemorySize, lds);
  (void)hipFuncSetAttribute(reinterpret_cast<const void*>(gru_kernel<1>),
                            hipFuncAttributeMaxDynamicSharedMemorySize, lds);

  gru_kernel<0><<<dim3(NBLK), dim3(384), lds, stream>>>(
      x, embb, Wih0, Whh0, bih0, bhh0, h0, y0, y0, hbuf, out + 32768, flags0);
  gru_kernel<1><<<dim3(NBLK), dim3(384), lds, stream>>>(
      x, embb, Wih1, Whh1, bih1, bhh1, h0 + NB * NH, y0, y0, hbuf,
      out + 32768 + NB * NH, flags1);
  logits_kernel<<<dim3(NB), dim3(256), 0, stream>>>(hbuf, fcW, fcb, out);
}

// Round 15
// 3736.120 us; speedup vs baseline: 1.4883x; 1.0608x over previous
//
#include <hip/hip_runtime.h>
#include <hip/hip_bf16.h>

using bf16x8 = __attribute__((ext_vector_type(8))) __bf16;
using short8 = __attribute__((ext_vector_type(8))) short;
using f32x4  = __attribute__((ext_vector_type(4))) float;
using f4     = __attribute__((ext_vector_type(4))) float;
using i32x4  = __attribute__((ext_vector_type(4))) int;

constexpr int NB = 128;    // batch
constexpr int NT = 256;    // time
constexpr int NH = 1024;   // hidden
constexpr int NE = 256;    // embed
constexpr int NV = 256;    // vocab

constexpr int WHH_BYTES = 48 * 2048;    // 98304: 48 rows x 1024 bf16
constexpr int GH_FLOATS = 30 * 256;     // 18 hh tiles + 12 input tiles
constexpr int NBLK = 256;

// ---- cache-bypass (coherence-point) memory ops: no bulk wbl2/inv needed ----
__device__ __forceinline__ void ldg_sc(i32x4& d, const void* p) {
  asm volatile("global_load_dwordx4 %0, %1, off sc0 sc1" : "=v"(d) : "v"(p));
}
__device__ __forceinline__ void ldg_c(i32x4& d, const void* p) {   // cached path
  asm volatile("global_load_dwordx4 %0, %1, off" : "=v"(d) : "v"(p));
}
__device__ __forceinline__ void stg_sc(void* p, i32x4 v) {
  asm volatile("global_store_dwordx4 %0, %1, off sc0 sc1" :: "v"(p), "v"(v) : "memory");
}
__device__ __forceinline__ void vm0_fence() {
  asm volatile("s_waitcnt vmcnt(0)" ::: "memory");
}
__device__ __forceinline__ void use_dep(i32x4& d) {
  asm volatile("" : "+v"(d));
}

// 8 contiguous f32 -> bf16x8 (RNE)
__device__ __forceinline__ bf16x8 cvt8(const float* p) {
  short8 r;
  #pragma unroll
  for (int j = 0; j < 8; ++j)
    r[j] = (short)__bfloat16_as_ushort(__float2bfloat16(p[j]));
  return __builtin_bit_cast(bf16x8, r);
}

__global__ __launch_bounds__(256) void embcvt_kernel(const float* __restrict__ e,
                                                     __hip_bfloat16* __restrict__ o) {
  int i = blockIdx.x * 256 + threadIdx.x;
  o[i] = __float2bfloat16(e[i]);
}

// 256 WGs x 384 threads. WG owns h'[rb*32:+32, c0:+16]. Wave wv=(mt,ks):
// hh GEMM = m-tile mt, K-slice ks, all 3 gates; input GEMM = gate ks,
// K-HALF mt. R15: L0 prefetches BOTH m-tiles' emb fragments one step ahead
// (x is static!) -- next xids load in the A-load shadow, emb loads issue
// after gates (latency hides under publish+flag RT), and the step-top
// input GEMM is pure register compute with partials written PRE-POLL.
// This removes L0's ~3us of divergent-gather work from the serial chain
// (publish -> poll), matching L1's prefetched structure.
template<int LAYER>
__global__ __launch_bounds__(384, 1) void gru_kernel(
    const int* __restrict__ x,
    const __hip_bfloat16* __restrict__ embb,
    const float* __restrict__ Wih,
    const float* __restrict__ Whh,
    const float* __restrict__ bih,
    const float* __restrict__ bhh,
    const float* __restrict__ h0,
    const __hip_bfloat16* __restrict__ yin,   // [T][B][H] (layer1 input)
    __hip_bfloat16* __restrict__ yout,        // [T][B][H] (layer0 output)
    __hip_bfloat16* __restrict__ hbuf,        // [2][128][1024]
    float* __restrict__ hout,
    unsigned int* __restrict__ flags)         // [4][64][16] uints
{
  extern __shared__ char smem[];
  char*  sWhh  = smem;
  float* sGh   = (float*)(smem + WHH_BYTES);
  float* sBias = sGh + GH_FLOATS;
  char*  sH    = (char*)(sBias + 64);         // 32x16 bf16 h' staging (1KB)

  const int tid  = threadIdx.x;
  const int lane = tid & 63;
  const int wv   = tid >> 6;
  const int mt   = wv & 1;
  const int ks   = wv >> 1;                   // K-slice / input gate, 0..2
  const int b    = blockIdx.x;
  const int rb   = (b >> 1) & 3;
  const int cidx = (b & 1) * 32 + (b >> 3);
  const int r0   = rb * 32;
  const int c0   = cidx * 16;
  unsigned int* pf = flags + rb * 64 * 16;
  const int slot = cidx;
  const int l16  = lane & 15;
  const int lk8  = (lane >> 4) * 8;

  // ---- stage W_hh slice swizzled (rows gate-major: gr>>4 = gate) ----
  for (int it = 0; it < 16; ++it) {
    int idx = it * 384 + tid;
    int gr = idx >> 7, kc = idx & 127;
    int grow = (gr >> 4) * NH + c0 + (gr & 15);
    short8 v = __builtin_bit_cast(short8, cvt8(Whh + grow * NH + kc * 8));
    *(short8*)(sWhh + ((gr * 2048 + kc * 16) ^ ((gr & 7) << 4))) = v;
  }
  if (tid < 16)       sBias[tid] = bih[c0 + tid] + bhh[c0 + tid];
  else if (tid < 32)  { int c = NH + c0 + tid - 16;   sBias[tid] = bih[c] + bhh[c]; }
  else if (tid < 48)  { int c = 2*NH + c0 + tid - 32; sBias[tid] = bih[c]; }
  else if (tid < 64)  { int c = 2*NH + c0 + tid - 48; sBias[tid] = bhh[c]; }

  // ---- W_ih VGPR fragments: gate ks, K-half mt (no spill) ----
  constexpr int KIN   = (LAYER == 0) ? NE : NH;
  constexpr int NFRAG = KIN / 64;             // L0: 4, L1: 16
  const int khalf = mt * (KIN / 2);
  bf16x8 wreg[NFRAG];
  #pragma unroll
  for (int kf = 0; kf < NFRAG; ++kf) {
    int grow = ks * NH + c0 + l16;
    wreg[kf] = cvt8(Wih + grow * KIN + khalf + kf * 32 + lk8);
  }

  // ---- init h0 -> regs + sH -> staged sc publish + flag=1 ----
  float hown[2] = {0.f, 0.f};
  #pragma unroll
  for (int ei = 0; ei < 2; ++ei) {
    int e = tid + ei * 384;
    if (e < 512) {
      float hv = h0[(r0 + (e >> 4)) * NH + c0 + (e & 15)];
      hown[ei] = hv;
      ((unsigned short*)sH)[e] = __bfloat16_as_ushort(__float2bfloat16(hv));
    }
  }
  __syncthreads();
  if (tid < 64) {
    i32x4 hv = *(const i32x4*)(sH + (tid >> 1) * 32 + (tid & 1) * 16);
    stg_sc(hbuf + (r0 + (tid >> 1)) * NH + c0 + (tid & 1) * 8, hv);
    vm0_fence();
    if (tid == 0)
      __hip_atomic_store(pf + slot * 16, 1u, __ATOMIC_RELAXED,
                         __HIP_MEMORY_SCOPE_AGENT);
  }

  // ---- prologue prefetch of step-0 input fragments ----
  i32x4 pe0[(LAYER == 0) ? 4 : 16];           // L0: m-tile0; L1: m-tile0
  i32x4 pe1[(LAYER == 0) ? 4 : 1];            // L0: m-tile1
  int xq0 = 0, xq1 = 0;
  if constexpr (LAYER == 0) {
    xq0 = x[(r0 + l16) * NT + 0];
    xq1 = x[(r0 + 16 + l16) * NT + 0];
    const __hip_bfloat16* e0 = embb + xq0 * NE + khalf + lk8;
    const __hip_bfloat16* e1 = embb + xq1 * NE + khalf + lk8;
    #pragma unroll
    for (int kf = 0; kf < 4; ++kf) { ldg_c(pe0[kf], e0 + kf * 32); ldg_c(pe1[kf], e1 + kf * 32); }
    vm0_fence();
    #pragma unroll
    for (int kf = 0; kf < 4; ++kf) { use_dep(pe0[kf]); use_dep(pe1[kf]); }
  } else {
    const __hip_bfloat16* yp = yin + ((size_t)0 * NB + (r0 + l16)) * NH + khalf + lk8;
    #pragma unroll
    for (int kf = 0; kf < 16; ++kf) ldg_c(pe0[kf], yp + kf * 32);
    vm0_fence();
    #pragma unroll
    for (int kf = 0; kf < 16; ++kf) use_dep(pe0[kf]);
  }

  // ---- time loop ----
  for (int t = 0; t < NT; ++t) {
    const __hip_bfloat16* rbuf = hbuf + (t & 1) * (NB * NH);
    __hip_bfloat16* wbuf = hbuf + ((t + 1) & 1) * (NB * NH);
    const int arow = r0 + mt * 16 + l16;
    const int bxor = (l16 & 7) << 4;
    float* abase = sGh + (lane >> 4) * 64 + l16;

    // ---- 1. input GEMM from prefetched regs (pure reg compute, PRE-POLL) ----
    f32x4 ai0 = {0.f,0.f,0.f,0.f}, ai1 = {0.f,0.f,0.f,0.f};
    vm0_fence();
    if constexpr (LAYER == 0) {
      #pragma unroll
      for (int kf = 0; kf < 4; ++kf) { use_dep(pe0[kf]); use_dep(pe1[kf]); }
      #pragma unroll
      for (int kf = 0; kf < 4; ++kf) {
        ai0 = __builtin_amdgcn_mfma_f32_16x16x32_bf16(
            __builtin_bit_cast(bf16x8, pe0[kf]), wreg[kf], ai0, 0, 0, 0);
        ai1 = __builtin_amdgcn_mfma_f32_16x16x32_bf16(
            __builtin_bit_cast(bf16x8, pe1[kf]), wreg[kf], ai1, 0, 0, 0);
      }
      // both input partials written pre-poll (tiles free since prev pre-publish barrier)
      float* pi0 = abase + (18 + (ks * 2 + mt) * 2 + 0) * 256;
      float* pi1 = abase + (18 + (ks * 2 + mt) * 2 + 1) * 256;
      pi0[0]=ai0[0]; pi0[16]=ai0[1]; pi0[32]=ai0[2]; pi0[48]=ai0[3];
      pi1[0]=ai1[0]; pi1[16]=ai1[1]; pi1[32]=ai1[2]; pi1[48]=ai1[3];
    } else {
      #pragma unroll
      for (int kf = 0; kf < 16; ++kf) use_dep(pe0[kf]);
      #pragma unroll
      for (int kf = 0; kf < 16; ++kf) {
        ai0 = __builtin_amdgcn_mfma_f32_16x16x32_bf16(
            __builtin_bit_cast(bf16x8, pe0[kf]), wreg[kf], ai0, 0, 0, 0);
      }
    }

    // ---- 2. wait for all producers of h(t) (wave0 polls padded flags) ----
    {
      unsigned int ep = (unsigned int)(t + 1);
      if (tid < 64) {
        const unsigned int* f = pf + tid * 16;
        while (__hip_atomic_load(f, __ATOMIC_RELAXED,
                                 __HIP_MEMORY_SCOPE_AGENT) < ep)
          __builtin_amdgcn_s_sleep(1);
      }
      __syncthreads();
    }

    // ---- 3a. issue ALL A sc-loads; L0 also next-step x ids (shadowed) ----
    const int nk = (ks < 2) ? 11 : 10;
    const __hip_bfloat16* aptr = rbuf + arow * NH + lk8;
    i32x4 fr[11];
    #pragma unroll
    for (int i = 0; i < 11; ++i)
      if (i < nk) ldg_sc(fr[i], aptr + (ks + 3 * i) * 32);
    if constexpr (LAYER == 0) {
      int tn = (t + 1 < NT) ? (t + 1) : (NT - 1);
      xq0 = x[(r0 + l16) * NT + tn];
      xq1 = x[(r0 + 16 + l16) * NT + tn];
    }

    // ---- 1b. (L1 only) input GEMM m-tile 1 (hides A-load round trip) ----
    if constexpr (LAYER == 1) {
      const __hip_bfloat16* xp1 = yin + ((size_t)t * NB + (r0 + 16 + l16)) * NH + khalf + lk8;
      #pragma unroll
      for (int kf = 0; kf < 16; ++kf) {
        bf16x8 a = __builtin_bit_cast(bf16x8, *(const short8*)(xp1 + kf * 32));
        ai1 = __builtin_amdgcn_mfma_f32_16x16x32_bf16(a, wreg[kf], ai1, 0, 0, 0);
      }
    }
    {   // input partials (L1; L0 already wrote pre-poll)
      if constexpr (LAYER == 1) {
        float* pi0 = abase + (18 + (ks * 2 + mt) * 2 + 0) * 256;
        float* pi1 = abase + (18 + (ks * 2 + mt) * 2 + 1) * 256;
        pi0[0]=ai0[0]; pi0[16]=ai0[1]; pi0[32]=ai0[2]; pi0[48]=ai0[3];
        pi1[0]=ai1[0]; pi1[16]=ai1[1]; pi1[32]=ai1[2]; pi1[48]=ai1[3];
      }
    }

    // ---- 3b. W_hh MFMAs: A from regs, all 3 gates per chunk ----
    vm0_fence();
    #pragma unroll
    for (int i = 0; i < 11; ++i)
      if (i < nk) use_dep(fr[i]);
    {
      f32x4 ah0 = {0.f,0.f,0.f,0.f}, ah1 = {0.f,0.f,0.f,0.f}, ah2 = {0.f,0.f,0.f,0.f};
      const int bb0 = (l16)      * 2048 + lk8 * 2;
      const int bb1 = (16 + l16) * 2048 + lk8 * 2;
      const int bb2 = (32 + l16) * 2048 + lk8 * 2;
      #pragma unroll
      for (int i = 0; i < 11; ++i) {
        if (i < nk) {
          int kk = ks + 3 * i;
          bf16x8 a = __builtin_bit_cast(bf16x8, fr[i]);
          bf16x8 b0 = __builtin_bit_cast(bf16x8,
              *(const short8*)(sWhh + ((bb0 + kk * 64) ^ bxor)));
          ah0 = __builtin_amdgcn_mfma_f32_16x16x32_bf16(a, b0, ah0, 0, 0, 0);
          bf16x8 b1 = __builtin_bit_cast(bf16x8,
              *(const short8*)(sWhh + ((bb1 + kk * 64) ^ bxor)));
          ah1 = __builtin_amdgcn_mfma_f32_16x16x32_bf16(a, b1, ah1, 0, 0, 0);
          bf16x8 b2 = __builtin_bit_cast(bf16x8,
              *(const short8*)(sWhh + ((bb2 + kk * 64) ^ bxor)));
          ah2 = __builtin_amdgcn_mfma_f32_16x16x32_bf16(a, b2, ah2, 0, 0, 0);
        }
      }
      // hh partials -> disjoint tiles [ks*6 + mt*3 + g]
      float* p0 = abase + (ks * 6 + mt * 3 + 0) * 256;
      float* p1 = abase + (ks * 6 + mt * 3 + 1) * 256;
      float* p2 = abase + (ks * 6 + mt * 3 + 2) * 256;
      p0[0]=ah0[0]; p0[16]=ah0[1]; p0[32]=ah0[2]; p0[48]=ah0[3];
      p1[0]=ah1[0]; p1[16]=ah1[1]; p1[32]=ah1[2]; p1[48]=ah1[3];
      p2[0]=ah2[0]; p2[16]=ah2[1]; p2[32]=ah2[2]; p2[48]=ah2[3];
    }
    __syncthreads();

    // ---- 4. gates: sum partials; h' -> sH only ----
    #pragma unroll
    for (int ei = 0; ei < 2; ++ei) {
      int e = tid + ei * 384;
      if (e < 512) {
        int lrow = e >> 4, lcol = e & 15;
        int m2 = lrow >> 4, off = (lrow & 15) * 16 + lcol;
        float ghr = sGh[(0*6 + m2*3 + 0) * 256 + off]
                  + sGh[(1*6 + m2*3 + 0) * 256 + off]
                  + sGh[(2*6 + m2*3 + 0) * 256 + off];
        float ghz = sGh[(0*6 + m2*3 + 1) * 256 + off]
                  + sGh[(1*6 + m2*3 + 1) * 256 + off]
                  + sGh[(2*6 + m2*3 + 1) * 256 + off];
        float ghn = sGh[(0*6 + m2*3 + 2) * 256 + off]
                  + sGh[(1*6 + m2*3 + 2) * 256 + off]
                  + sGh[(2*6 + m2*3 + 2) * 256 + off];
        float gir = sGh[(18 + (0*2+0)*2 + m2) * 256 + off]
                  + sGh[(18 + (0*2+1)*2 + m2) * 256 + off];
        float giz = sGh[(18 + (1*2+0)*2 + m2) * 256 + off]
                  + sGh[(18 + (1*2+1)*2 + m2) * 256 + off];
        float gin = sGh[(18 + (2*2+0)*2 + m2) * 256 + off]
                  + sGh[(18 + (2*2+1)*2 + m2) * 256 + off];
        float r = 1.f / (1.f + __expf(-(gir + ghr + sBias[lcol])));
        float z = 1.f / (1.f + __expf(-(giz + ghz + sBias[16 + lcol])));
        float npre = (gin + sBias[32 + lcol]) + r * (ghn + sBias[48 + lcol]);
        float n = 2.f / (1.f + __expf(-2.f * npre)) - 1.f;   // tanh, inf-safe
        float hn = (1.f - z) * n + z * hown[ei];
        hown[ei] = hn;
        ((unsigned short*)sH)[e] = __bfloat16_as_ushort(__float2bfloat16(hn));
      }
    }

    // ---- 4b. prefetch next period's input fragments ----
    if constexpr (LAYER == 0) {
      const __hip_bfloat16* e0 = embb + xq0 * NE + khalf + lk8;
      const __hip_bfloat16* e1 = embb + xq1 * NE + khalf + lk8;
      #pragma unroll
      for (int kf = 0; kf < 4; ++kf) { ldg_c(pe0[kf], e0 + kf * 32); ldg_c(pe1[kf], e1 + kf * 32); }
    } else {
      int tn = (t + 1 < NT) ? (t + 1) : (NT - 1);
      const __hip_bfloat16* yp = yin + ((size_t)tn * NB + (r0 + l16)) * NH + khalf + lk8;
      #pragma unroll
      for (int kf = 0; kf < 16; ++kf) ldg_c(pe0[kf], yp + kf * 32);
    }

    // ---- 5. publish h' (wave0, sc) + flag; wave1 stores y0 (off-chain) ----
    __syncthreads();
    if constexpr (LAYER == 0) {
      if (tid >= 64 && tid < 128) {
        int l = tid & 63;
        i32x4 hv = *(const i32x4*)(sH + (l >> 1) * 32 + (l & 1) * 16);
        *(i32x4*)(yout + ((size_t)t * NB + (r0 + (l >> 1))) * NH + c0 + (l & 1) * 8) = hv;
      }
    }
    if (tid < 64) {
      i32x4 hv = *(const i32x4*)(sH + (tid >> 1) * 32 + (tid & 1) * 16);
      stg_sc(wbuf + (r0 + (tid >> 1)) * NH + c0 + (tid & 1) * 8, hv);
      vm0_fence();
      if (tid == 0)
        __hip_atomic_store(pf + slot * 16, (unsigned int)(t + 2),
                           __ATOMIC_RELAXED, __HIP_MEMORY_SCOPE_AGENT);
    }
  }

  #pragma unroll
  for (int ei = 0; ei < 2; ++ei) {
    int e = tid + ei * 384;
    if (e < 512) {
      int lrow = e >> 4, lcol = e & 15;
      hout[(r0 + lrow) * NH + c0 + lcol] = hown[ei];
    }
  }
}

__global__ __launch_bounds__(256) void logits_kernel(
    const __hip_bfloat16* __restrict__ h1,
    const float* __restrict__ fcW,
    const float* __restrict__ fcb,
    float* __restrict__ out)
{
  __shared__ float hrow[NH];
  int b = blockIdx.x, v = threadIdx.x;
  if (v < 128) {
    i32x4 hv;
    ldg_sc(hv, h1 + b * NH + v * 8);
    vm0_fence();
    use_dep(hv);
    short8 s = __builtin_bit_cast(short8, hv);
    #pragma unroll
    for (int j = 0; j < 8; ++j) {
      union { unsigned int i; float f; } c;
      c.i = ((unsigned int)(unsigned short)s[j]) << 16;
      hrow[v * 8 + j] = c.f;
    }
  }
  __syncthreads();
  float acc = fcb[v];
  for (int k = 0; k < NH; k += 4) {
    f4 wv = *(const f4*)(fcW + v * NH + k);
    #pragma unroll
    for (int j = 0; j < 4; ++j) acc += wv[j] * hrow[k + j];
  }
  out[b * NV + v] = acc;
}

extern "C" void kernel_launch(void* const* d_in, const int* in_sizes, int n_in,
                              void* d_out, int out_size, void* d_ws, size_t ws_size,
                              hipStream_t stream) {
  const int*   x    = (const int*)d_in[0];
  const float* h0   = (const float*)d_in[1];
  const float* emb  = (const float*)d_in[2];
  const float* Wih0 = (const float*)d_in[3];
  const float* Whh0 = (const float*)d_in[4];
  const float* bih0 = (const float*)d_in[5];
  const float* bhh0 = (const float*)d_in[6];
  const float* Wih1 = (const float*)d_in[7];
  const float* Whh1 = (const float*)d_in[8];
  const float* bih1 = (const float*)d_in[9];
  const float* bhh1 = (const float*)d_in[10];
  const float* fcW  = (const float*)d_in[11];
  const float* fcb  = (const float*)d_in[12];
  float* out = (float*)d_out;

  char* ws = (char*)d_ws;
  size_t off = 0;
  __hip_bfloat16* y0   = (__hip_bfloat16*)ws;            off += (size_t)NB * NT * NH * 2;  // [T][B][H]
  __hip_bfloat16* hbuf = (__hip_bfloat16*)(ws + off);    off += (size_t)2 * NB * NH * 2;
  __hip_bfloat16* embb = (__hip_bfloat16*)(ws + off);    off += (size_t)NV * NE * 2;
  unsigned int*  flags0 = (unsigned int*)(ws + off);     off += 4 * 64 * 16 * 4;
  unsigned int*  flags1 = (unsigned int*)(ws + off);     off += 4 * 64 * 16 * 4;

  (void)hipMemsetAsync(flags0, 0, 2 * 4 * 64 * 16 * 4, stream);
  embcvt_kernel<<<dim3(NV * NE / 256), dim3(256), 0, stream>>>(emb, embb);

  constexpr int lds = WHH_BYTES + GH_FLOATS * 4 + 64 * 4 + 1024;  // 130304
  (void)hipFuncSetAttribute(reinterpret_cast<const void*>(gru_kernel<0>),
                            hipFuncAttributeMaxDynamicSharedMemorySize, lds);
  (void)hipFuncSetAttribute(reinterpret_cast<const void*>(gru_kernel<1>),
                            hipFuncAttributeMaxDynamicSharedMemorySize, lds);

  gru_kernel<0><<<dim3(NBLK), dim3(384), lds, stream>>>(
      x, embb, Wih0, Whh0, bih0, bhh0, h0, y0, y0, hbuf, out + 32768, flags0);
  gru_kernel<1><<<dim3(NBLK), dim3(384), lds, stream>>>(
      x, embb, Wih1, Whh1, bih1, bhh1, h0 + NB * NH, y0, y0, hbuf,
      out + 32768 + NB * NH, flags1);
  logits_kernel<<<dim3(NB), dim3(256), 0, stream>>>(hbuf, fcW, fcb, out);
}